// Round 3
// baseline (1307.656 us; speedup 1.0000x reference)
//
#include <hip/hip_runtime.h>
#include <cstdint>
#include <cstddef>

#define DEVI __device__ __forceinline__

typedef __attribute__((ext_vector_type(8))) short short8;
typedef __attribute__((ext_vector_type(4))) float f32x4;

static constexpr int kS = 1024, kH = 32;
static constexpr int kM = 2048;      // B*S
static constexpr float kInvSqrtHD = 0.08838834764831845f; // 1/sqrt(128)

// ---------------- ws layout (bytes). Peak ~160.5 MB. ----------------
// Region A (112MB): phase1 [hs_b 16MB | wqkv_b 96MB] -> phase2 [qq 16|kq 16|vt 16|ao 32|aob 16]
static constexpr size_t OFF_A    = 0;
static constexpr size_t A_HSB    = 0;          // bf16 [2048][4096]
static constexpr size_t A_WQKV   = 16777216;   // bf16 [12288][4096]
static constexpr size_t A_QQ     = 0;          // bf16(int) [64][1024][128]
static constexpr size_t A_KQ     = 16777216;   // bf16(int) [64][1024][128]
static constexpr size_t A_VT     = 33554432;   // bf16(int) [64][128][1024]
static constexpr size_t A_AO     = 50331648;   // f32 [64][1024][128]
static constexpr size_t A_AOB    = 83886080;   // bf16(int) [2048][4096]
static constexpr size_t OFF_QKV  = 117440512;  // bf16 [2048][12288] (48MB); later wo_b bf16 [4096][4096] (32MB)
static constexpr size_t OFF_TAB  = 167772160;  // f32 cos[1024][64], sin[1024][64]
static constexpr size_t OFF_RED  = 168296448;  // u32 red[0]=maxq 1=maxk 2=maxv 3=maxdot 4=maxao

// ---------------- helpers ----------------
DEVI unsigned short f2bf(float x) {             // RNE f32 -> bf16
  unsigned u = __float_as_uint(x);
  return (unsigned short)((u + 0x7FFFu + ((u >> 16) & 1u)) >> 16);
}
DEVI float bf2f(short u) { return __uint_as_float(((unsigned)(unsigned short)u) << 16); }

DEVI void gload_lds16(const void* g, void* l) { // async global->LDS, 16B/lane
  __builtin_amdgcn_global_load_lds((const __attribute__((address_space(1))) unsigned int*)g,
                                   (__attribute__((address_space(3))) unsigned int*)l,
                                   16, 0, 0);
}
DEVI f32x4 mfma16(short8 a, short8 b, f32x4 c) {
  return __builtin_amdgcn_mfma_f32_16x16x32_bf16(a, b, c, 0, 0, 0);
}
DEVI float wave_max(float v) {
  #pragma unroll
  for (int o = 32; o; o >>= 1) v = fmaxf(v, __shfl_xor(v, o));
  return v;
}
DEVI float wave_sum(float v) {
  #pragma unroll
  for (int o = 32; o; o >>= 1) v += __shfl_xor(v, o);
  return v;
}
DEVI float clamp127(float x) { return fminf(fmaxf(x, -127.0f), 127.0f); }

// ---------------- K1: fp32 -> bf16 of hs + wq,wk,wv ----------------
__global__ __launch_bounds__(256) void convert_hqkv(
    const float* __restrict__ hs, const float* __restrict__ wq,
    const float* __restrict__ wk, const float* __restrict__ wv,
    unsigned short* __restrict__ hs_b, unsigned short* __restrict__ wqkv_b)
{
  const size_t NHS = 8388608ULL, WN = 16777216ULL;
  const size_t n4 = (NHS + 3 * WN) / 4;
  for (size_t i4 = (size_t)blockIdx.x * 256 + threadIdx.x; i4 < n4;
       i4 += (size_t)gridDim.x * 256) {
    size_t i = i4 * 4;
    const float* src; unsigned short* dst;
    if (i < NHS) { src = hs + i; dst = hs_b + i; }
    else {
      size_t j = i - NHS;
      src = (j < WN) ? (wq + j) : (j < 2 * WN) ? (wk + (j - WN)) : (wv + (j - 2 * WN));
      dst = wqkv_b + j;
    }
    float4 v = *(const float4*)src;
    unsigned long long p =
        (unsigned long long)f2bf(v.x) | ((unsigned long long)f2bf(v.y) << 16) |
        ((unsigned long long)f2bf(v.z) << 32) | ((unsigned long long)f2bf(v.w) << 48);
    *(unsigned long long*)dst = p;
  }
}

// ---------------- K1b: fp32 -> bf16 of wo (runs late, into dead qkv region) ----------------
__global__ __launch_bounds__(256) void convert_wo(
    const float* __restrict__ wo, unsigned short* __restrict__ wo_b)
{
  const size_t n4 = 16777216ULL / 4;
  for (size_t i4 = (size_t)blockIdx.x * 256 + threadIdx.x; i4 < n4;
       i4 += (size_t)gridDim.x * 256) {
    size_t i = i4 * 4;
    float4 v = *(const float4*)(wo + i);
    unsigned long long p =
        (unsigned long long)f2bf(v.x) | ((unsigned long long)f2bf(v.y) << 16) |
        ((unsigned long long)f2bf(v.z) << 32) | ((unsigned long long)f2bf(v.w) << 48);
    *(unsigned long long*)(wo_b + i) = p;
  }
}

// ---------------- K0: RoPE cos/sin table [1024][64] ----------------
__global__ void rope_table(float* __restrict__ ct, float* __restrict__ st) {
  int i = blockIdx.x * blockDim.x + threadIdx.x;
  if (i >= kS * 64) return;
  int s = i >> 6, j = i & 63;
  float invf = 1.0f / powf(10000.0f, (float)j / 64.0f);
  float fr = (float)s * invf;
  ct[i] = cosf(fr);
  st[i] = sinf(fr);
}

// ---------------- GEMM: C[M][N] = A[M][K]bf16 @ Bt[N][K]bf16; OUTBF: bf16 C ----------------
template <int OUTBF>
__global__ __launch_bounds__(256) void gemm_nt(
    const unsigned short* __restrict__ A, const unsigned short* __restrict__ Bt,
    void* __restrict__ Cv, int M, int N, int K,
    const unsigned* __restrict__ red, int redidx)
{
  __shared__ __align__(16) unsigned short As[128 * 64];
  __shared__ __align__(16) unsigned short Bs[128 * 64];
  const int tid = threadIdx.x, l = tid & 63, w = tid >> 6;
  const int m0 = blockIdx.y * 128, n0 = blockIdx.x * 128;
  const int wr = w >> 1, wc = w & 1;
  const int lrow = l >> 3, lsl = l & 7;
  const int srcks = lsl ^ lrow;        // pre-swizzled global k-slot (rule #21)
  f32x4 acc[4][4];
  #pragma unroll
  for (int a = 0; a < 4; ++a)
    #pragma unroll
    for (int b = 0; b < 4; ++b) { acc[a][b][0] = 0.f; acc[a][b][1] = 0.f; acc[a][b][2] = 0.f; acc[a][b][3] = 0.f; }

  for (int k0 = 0; k0 < K; k0 += 64) {
    #pragma unroll
    for (int j = 0; j < 4; ++j) {
      int c = w * 4 + j;
      int row = c * 8 + lrow;
      gload_lds16(A  + (size_t)(m0 + row) * K + k0 + srcks * 8, (char*)As + c * 1024);
      gload_lds16(Bt + (size_t)(n0 + row) * K + k0 + srcks * 8, (char*)Bs + c * 1024);
    }
    __syncthreads();
    #pragma unroll
    for (int kk = 0; kk < 2; ++kk) {
      short8 af[4], bf[4];
      #pragma unroll
      for (int mi = 0; mi < 4; ++mi) {
        int row = wr * 64 + mi * 16 + (l & 15);
        int slot = (kk * 4 + (l >> 4)) ^ (row & 7);
        af[mi] = *(const short8*)((const char*)As + row * 128 + slot * 16);
      }
      #pragma unroll
      for (int ni = 0; ni < 4; ++ni) {
        int row = wc * 64 + ni * 16 + (l & 15);
        int slot = (kk * 4 + (l >> 4)) ^ (row & 7);
        bf[ni] = *(const short8*)((const char*)Bs + row * 128 + slot * 16);
      }
      #pragma unroll
      for (int mi = 0; mi < 4; ++mi)
        #pragma unroll
        for (int ni = 0; ni < 4; ++ni)
          acc[mi][ni] = mfma16(af[mi], bf[ni], acc[mi][ni]);
    }
    __syncthreads();
  }

  float alpha = 1.0f;
  if (redidx >= 0) alpha = fmaxf(__uint_as_float(red[redidx]), 1e-8f) / 127.0f;
  #pragma unroll
  for (int mi = 0; mi < 4; ++mi) {
    int row = m0 + wr * 64 + mi * 16 + (l >> 4) * 4;
    #pragma unroll
    for (int ni = 0; ni < 4; ++ni) {
      int col = n0 + wc * 64 + ni * 16 + (l & 15);
      #pragma unroll
      for (int i = 0; i < 4; ++i) {
        float v = acc[mi][ni][i] * alpha;
        if constexpr (OUTBF) ((unsigned short*)Cv)[(size_t)(row + i) * N + col] = f2bf(v);
        else                 ((float*)Cv)[(size_t)(row + i) * N + col] = v;
      }
    }
  }
}

// ---------------- K3: read bf16 qkv, apply rope (no store), absmax q,k,v ----------------
__global__ __launch_bounds__(256) void rope_absmax(
    const unsigned short* __restrict__ qkv, const int* __restrict__ pos,
    const float* __restrict__ ct, const float* __restrict__ st,
    unsigned* __restrict__ red)
{
  int bs = blockIdx.x, t = threadIdx.x;
  int p = pos[bs];
  const unsigned short* row = qkv + (size_t)bs * 12288;
  int h = t >> 3, jc = (t & 7) * 8;
  float cs[8], sn[8];
  #pragma unroll
  for (int e = 0; e < 8; ++e) { cs[e] = ct[p * 64 + jc + e]; sn[e] = st[p * 64 + jc + e]; }
  float mq = 0.f, mk = 0.f, mv = 0.f;
  {
    short8 x1 = *(const short8*)(row + h * 128 + jc);
    short8 x2 = *(const short8*)(row + h * 128 + 64 + jc);
    #pragma unroll
    for (int e = 0; e < 8; ++e) {
      float a = bf2f(x1[e]), b = bf2f(x2[e]);
      mq = fmaxf(mq, fmaxf(fabsf(a * cs[e] - b * sn[e]), fabsf(b * cs[e] + a * sn[e])));
    }
  }
  {
    short8 x1 = *(const short8*)(row + 4096 + h * 128 + jc);
    short8 x2 = *(const short8*)(row + 4096 + h * 128 + 64 + jc);
    #pragma unroll
    for (int e = 0; e < 8; ++e) {
      float a = bf2f(x1[e]), b = bf2f(x2[e]);
      mk = fmaxf(mk, fmaxf(fabsf(a * cs[e] - b * sn[e]), fabsf(b * cs[e] + a * sn[e])));
    }
  }
  {
    short8 v0 = *(const short8*)(row + 8192 + t * 16);
    short8 v1 = *(const short8*)(row + 8192 + t * 16 + 8);
    #pragma unroll
    for (int e = 0; e < 8; ++e) mv = fmaxf(mv, fmaxf(fabsf(bf2f(v0[e])), fabsf(bf2f(v1[e]))));
  }
  mq = wave_max(mq); mk = wave_max(mk); mv = wave_max(mv);
  if ((t & 63) == 0) {
    atomicMax(red + 0, __float_as_uint(mq));
    atomicMax(red + 1, __float_as_uint(mk));
    atomicMax(red + 2, __float_as_uint(mv));
  }
}

// ---------------- K4: re-apply rope, quantize q,k -> [b][h][s][128] int-bf16 ----------------
__global__ __launch_bounds__(256) void quant_qk_rope(
    const unsigned short* __restrict__ qkv, const int* __restrict__ pos,
    const float* __restrict__ ct, const float* __restrict__ st,
    const unsigned* __restrict__ red,
    unsigned short* __restrict__ qq, unsigned short* __restrict__ kq)
{
  int bs = blockIdx.x, t = threadIdx.x;
  int b = bs >> 10, s = bs & 1023;
  int p = pos[bs];
  float iq = 127.0f / fmaxf(__uint_as_float(red[0]), 1e-8f);
  float ik = 127.0f / fmaxf(__uint_as_float(red[1]), 1e-8f);
  const unsigned short* row = qkv + (size_t)bs * 12288;
  int h = t >> 3, jc = (t & 7) * 8;
  float cs[8], sn[8];
  #pragma unroll
  for (int e = 0; e < 8; ++e) { cs[e] = ct[p * 64 + jc + e]; sn[e] = st[p * 64 + jc + e]; }
  size_t ob = ((size_t)(b * kH + h) * kS + s) * 128;
  {
    short8 x1 = *(const short8*)(row + h * 128 + jc);
    short8 x2 = *(const short8*)(row + h * 128 + 64 + jc);
    short8 o1, o2;
    #pragma unroll
    for (int e = 0; e < 8; ++e) {
      float a = bf2f(x1[e]), b2 = bf2f(x2[e]);
      o1[e] = (short)f2bf(clamp127(rintf((a * cs[e] - b2 * sn[e]) * iq)));
      o2[e] = (short)f2bf(clamp127(rintf((b2 * cs[e] + a * sn[e]) * iq)));
    }
    *(short8*)(qq + ob + jc) = o1;
    *(short8*)(qq + ob + 64 + jc) = o2;
  }
  {
    short8 x1 = *(const short8*)(row + 4096 + h * 128 + jc);
    short8 x2 = *(const short8*)(row + 4096 + h * 128 + 64 + jc);
    short8 o1, o2;
    #pragma unroll
    for (int e = 0; e < 8; ++e) {
      float a = bf2f(x1[e]), b2 = bf2f(x2[e]);
      o1[e] = (short)f2bf(clamp127(rintf((a * cs[e] - b2 * sn[e]) * ik)));
      o2[e] = (short)f2bf(clamp127(rintf((b2 * cs[e] + a * sn[e]) * ik)));
    }
    *(short8*)(kq + ob + jc) = o1;
    *(short8*)(kq + ob + 64 + jc) = o2;
  }
}

// ---------------- K5: quantize + transpose v -> [b*h][hd][s] int-bf16 ----------------
__global__ __launch_bounds__(256) void quantT_v(
    const unsigned short* __restrict__ qkv, const unsigned* __restrict__ red,
    unsigned short* __restrict__ vt)
{
  __shared__ float tile[32][132];
  int bh = blockIdx.x, st0 = blockIdx.y * 32;
  int b = bh >> 5, h = bh & 31;
  float iv = 127.0f / fmaxf(__uint_as_float(red[2]), 1e-8f);
  int t = threadIdx.x;
  #pragma unroll
  for (int e = 0; e < 2; ++e) {
    int idx = (e * 256 + t) * 8;
    int sl = idx >> 7, hd = idx & 127;
    short8 xv = *(const short8*)(qkv + (size_t)(b * 1024 + st0 + sl) * 12288 + 8192 + h * 128 + hd);
    #pragma unroll
    for (int q = 0; q < 8; ++q) tile[sl][hd + q] = clamp127(rintf(bf2f(xv[q]) * iv));
  }
  __syncthreads();
  #pragma unroll
  for (int e = 0; e < 16; ++e) {
    int idx = e * 256 + t;
    int sl = idx & 31, hd = idx >> 5;
    vt[((size_t)bh * 128 + hd) * kS + st0 + sl] = f2bf(tile[sl][hd]);
  }
}

// ---------------- K6: QK^T integer absmax (full matrix, pre-mask) ----------------
__global__ __launch_bounds__(256) void qk_absmax(
    const unsigned short* __restrict__ qq, const unsigned short* __restrict__ kq,
    unsigned* __restrict__ red)
{
  int bh = blockIdx.x, r0 = blockIdx.y * 32;
  int t = threadIdx.x, l = t & 63, w = t >> 6;
  const unsigned short* qb = qq + (size_t)bh * 131072;
  const unsigned short* kb = kq + (size_t)bh * 131072;
  short8 aq[2][4];
  #pragma unroll
  for (int rg = 0; rg < 2; ++rg)
    #pragma unroll
    for (int s = 0; s < 4; ++s)
      aq[rg][s] = *(const short8*)(qb + (size_t)(r0 + rg * 16 + (l & 15)) * 128 + s * 32 + (l >> 4) * 8);
  float vmax = 0.f;
  for (int kt = 0; kt < 16; ++kt) {
    int key0 = w * 256 + kt * 16;
    short8 bq[4];
    #pragma unroll
    for (int s = 0; s < 4; ++s)
      bq[s] = *(const short8*)(kb + (size_t)(key0 + (l & 15)) * 128 + s * 32 + (l >> 4) * 8);
    #pragma unroll
    for (int rg = 0; rg < 2; ++rg) {
      f32x4 acc; acc[0] = 0.f; acc[1] = 0.f; acc[2] = 0.f; acc[3] = 0.f;
      #pragma unroll
      for (int s = 0; s < 4; ++s) acc = mfma16(aq[rg][s], bq[s], acc);
      #pragma unroll
      for (int i = 0; i < 4; ++i) vmax = fmaxf(vmax, fabsf(acc[i]));
    }
  }
  vmax = wave_max(vmax);
  if (l == 0) atomicMax(red + 3, __float_as_uint(vmax));
}

// ---------------- K7: fused QK^T -> quant -> mask -> softmax -> quant -> PV -> absmax ----------------
__global__ __launch_bounds__(256) void softmax_pv(
    const unsigned short* __restrict__ qq, const unsigned short* __restrict__ kq,
    const unsigned short* __restrict__ vt,
    unsigned* __restrict__ red, float* __restrict__ ao)
{
  __shared__ float Lg[16][1024];       // 64 KB, XOR-swizzled cols
  int bh = blockIdx.x, r0 = blockIdx.y * 16;
  int t = threadIdx.x, l = t & 63, w = t >> 6;
  float sq = fmaxf(__uint_as_float(red[0]), 1e-8f) / 127.0f;
  float sk = fmaxf(__uint_as_float(red[1]), 1e-8f) / 127.0f;
  const float c1 = sq * sk * kInvSqrtHD;           // int_dot -> attn_weight
  float sl = fmaxf(__uint_as_float(red[3]) * c1, 1e-8f) / 127.0f;
  float isl = 1.0f / sl;
  const unsigned short* qb = qq + (size_t)bh * 131072;
  const unsigned short* kb = kq + (size_t)bh * 131072;
  const unsigned short* vb = vt + (size_t)bh * 131072;

  // phase 1: QK^T, quantize logits, causal mask -> LDS
  short8 aq[4];
  #pragma unroll
  for (int s = 0; s < 4; ++s)
    aq[s] = *(const short8*)(qb + (size_t)(r0 + (l & 15)) * 128 + s * 32 + (l >> 4) * 8);
  for (int kt = 0; kt < 16; ++kt) {
    int key0 = w * 256 + kt * 16;
    short8 bq[4];
    #pragma unroll
    for (int s = 0; s < 4; ++s)
      bq[s] = *(const short8*)(kb + (size_t)(key0 + (l & 15)) * 128 + s * 32 + (l >> 4) * 8);
    f32x4 acc; acc[0] = 0.f; acc[1] = 0.f; acc[2] = 0.f; acc[3] = 0.f;
    #pragma unroll
    for (int s = 0; s < 4; ++s) acc = mfma16(aq[s], bq[s], acc);
    int col = key0 + (l & 15);
    #pragma unroll
    for (int i = 0; i < 4; ++i) {
      int rl = (l >> 4) * 4 + i;
      float qv = clamp127(rintf(acc[i] * c1 * isl)) * sl;
      if (col > r0 + rl) qv = -1e9f;
      Lg[rl][col ^ ((rl & 7) << 3)] = qv;
    }
  }
  __syncthreads();

  // phase 2: per-row softmax + prob quantization (int value stored as f32)
  #pragma unroll
  for (int r = 0; r < 4; ++r) {
    int row = w * 4 + r, xm = (row & 7) << 3;
    float m = -3.4e38f;
    #pragma unroll
    for (int j = 0; j < 16; ++j) m = fmaxf(m, Lg[row][(l + j * 64) ^ xm]);
    m = wave_max(m);
    float e[16], sum = 0.f;
    #pragma unroll
    for (int j = 0; j < 16; ++j) { e[j] = __expf(Lg[row][(l + j * 64) ^ xm] - m); sum += e[j]; }
    sum = wave_sum(sum);
    float inv = 1.0f / sum;
    #pragma unroll
    for (int j = 0; j < 16; ++j)
      Lg[row][(l + j * 64) ^ xm] = rintf(e[j] * inv * 127.0f);
  }
  __syncthreads();

  // phase 3: PV — wave w owns hd tiles {2w, 2w+1}
  float sv = fmaxf(__uint_as_float(red[2]), 1e-8f) / 127.0f;
  const float c2 = sv * (1.0f / 127.0f);
  f32x4 pacc[2];
  pacc[0][0]=0.f;pacc[0][1]=0.f;pacc[0][2]=0.f;pacc[0][3]=0.f;
  pacc[1][0]=0.f;pacc[1][1]=0.f;pacc[1][2]=0.f;pacc[1][3]=0.f;
  for (int ks = 0; ks < 32; ++ks) {
    int r = l & 15, c0 = ks * 32 + (l >> 4) * 8;
    int cx = c0 ^ ((r & 7) << 3);
    f32x4 f0 = *(const f32x4*)&Lg[r][cx];
    f32x4 f1 = *(const f32x4*)&Lg[r][cx + 4];
    short8 af;
    #pragma unroll
    for (int e = 0; e < 4; ++e) { af[e] = (short)f2bf(f0[e]); af[e + 4] = (short)f2bf(f1[e]); }
    #pragma unroll
    for (int j = 0; j < 2; ++j) {
      int hd = (w * 2 + j) * 16 + (l & 15);
      short8 bf = *(const short8*)(vb + (size_t)hd * kS + ks * 32 + (l >> 4) * 8);
      pacc[j] = mfma16(af, bf, pacc[j]);
    }
  }
  float vmax = 0.f;
  #pragma unroll
  for (int j = 0; j < 2; ++j) {
    int hd = (w * 2 + j) * 16 + (l & 15);
    int rbase = r0 + (l >> 4) * 4;
    #pragma unroll
    for (int i = 0; i < 4; ++i) {
      float val = pacc[j][i] * c2;
      ao[((size_t)bh * kS + rbase + i) * 128 + hd] = val;
      vmax = fmaxf(vmax, fabsf(val));
    }
  }
  vmax = wave_max(vmax);
  if (l == 0) atomicMax(red + 4, __float_as_uint(vmax));
}

// ---------------- K8: quantize attn_out -> int-bf16 [b][s][h*128+hd] ----------------
__global__ __launch_bounds__(256) void quant_ao(
    const float* __restrict__ ao, const unsigned* __restrict__ red,
    unsigned short* __restrict__ aob)
{
  float ia = 127.0f / fmaxf(__uint_as_float(red[4]), 1e-8f);
  const int n = 64 * kS * 128;
  for (int i = blockIdx.x * 256 + threadIdx.x; i < n; i += gridDim.x * 256) {
    int bh = i >> 17, rem = i & 131071;
    int s = rem >> 7, hd = rem & 127;
    int b = bh >> 5, h = bh & 31;
    aob[((size_t)(b * 1024 + s)) * 4096 + h * 128 + hd] = f2bf(clamp127(rintf(ao[i] * ia)));
  }
}

// ---------------- launch ----------------
extern "C" void kernel_launch(void* const* d_in, const int* in_sizes, int n_in,
                              void* d_out, int out_size, void* d_ws, size_t ws_size,
                              hipStream_t stream) {
  const float* hs = (const float*)d_in[0];
  const float* wq = (const float*)d_in[1];
  const float* wk = (const float*)d_in[2];
  const float* wv = (const float*)d_in[3];
  const float* wo = (const float*)d_in[4];
  const int* pos  = (const int*)d_in[5];
  char* ws = (char*)d_ws;

  unsigned short* hs_b   = (unsigned short*)(ws + OFF_A + A_HSB);
  unsigned short* wqkv_b = (unsigned short*)(ws + OFF_A + A_WQKV);
  unsigned short* qq     = (unsigned short*)(ws + OFF_A + A_QQ);
  unsigned short* kq     = (unsigned short*)(ws + OFF_A + A_KQ);
  unsigned short* vt     = (unsigned short*)(ws + OFF_A + A_VT);
  float*          ao     = (float*)(ws + OFF_A + A_AO);
  unsigned short* aob    = (unsigned short*)(ws + OFF_A + A_AOB);
  unsigned short* qkv    = (unsigned short*)(ws + OFF_QKV);
  unsigned short* wo_b   = (unsigned short*)(ws + OFF_QKV);   // after qkv is dead
  float*          rc     = (float*)(ws + OFF_TAB);
  float*          rs     = (float*)(ws + OFF_TAB + 262144);
  unsigned*       red    = (unsigned*)(ws + OFF_RED);

  (void)hipMemsetAsync(red, 0, 256, stream);

  rope_table<<<dim3(256), dim3(256), 0, stream>>>(rc, rs);
  convert_hqkv<<<dim3(2048), dim3(256), 0, stream>>>(hs, wq, wk, wv, hs_b, wqkv_b);
  gemm_nt<1><<<dim3(96, 16), dim3(256), 0, stream>>>(hs_b, wqkv_b, qkv, kM, 12288, 4096, red, -1);
  rope_absmax<<<dim3(2048), dim3(256), 0, stream>>>(qkv, pos, rc, rs, red);
  quant_qk_rope<<<dim3(2048), dim3(256), 0, stream>>>(qkv, pos, rc, rs, red, qq, kq);
  quantT_v<<<dim3(64, 32), dim3(256), 0, stream>>>(qkv, red, vt);
  convert_wo<<<dim3(1024), dim3(256), 0, stream>>>(wo, wo_b);
  qk_absmax<<<dim3(64, 32), dim3(256), 0, stream>>>(qq, kq, red);
  softmax_pv<<<dim3(64, 64), dim3(256), 0, stream>>>(qq, kq, vt, red, ao);
  quant_ao<<<dim3(2048), dim3(256), 0, stream>>>(ao, red, aob);
  gemm_nt<0><<<dim3(32, 16), dim3(256), 0, stream>>>(aob, wo_b, d_out, kM, 4096, 4096, red, 4);
}

// Round 4
// 1194.670 us; speedup vs baseline: 1.0946x; 1.0946x over previous
//
#include <hip/hip_runtime.h>
#include <cstdint>
#include <cstddef>

#define DEVI __device__ __forceinline__

typedef __attribute__((ext_vector_type(8))) short short8;
typedef __attribute__((ext_vector_type(4))) float f32x4;

static constexpr int kS = 1024, kH = 32;
static constexpr int kM = 2048;      // B*S
static constexpr float kInvSqrtHD = 0.08838834764831845f; // 1/sqrt(128)
static constexpr float kMaskVal = -3.0e38f;  // masked-logit marker (exp -> 0 for any sl >= 8e-11)

// ---------------- ws layout (bytes). Peak ~160.5 MB. ----------------
static constexpr size_t OFF_A    = 0;
static constexpr size_t A_HSB    = 0;          // bf16 [2048][4096]
static constexpr size_t A_WQKV   = 16777216;   // bf16 [12288][4096]
static constexpr size_t A_QQ     = 0;          // bf16(int) [64][1024][128]
static constexpr size_t A_KQ     = 16777216;   // bf16(int) [64][1024][128]
static constexpr size_t A_VT     = 33554432;   // bf16(int) [64][128][1024]
static constexpr size_t A_AO     = 50331648;   // f32 [64][1024][128]
static constexpr size_t A_AOB    = 83886080;   // bf16(int) [2048][4096]
static constexpr size_t OFF_QKV  = 117440512;  // bf16 [2048][12288] (48MB); later wo_b (32MB)
static constexpr size_t OFF_TAB  = 167772160;  // f32 cos[1024][64], sin[1024][64]
static constexpr size_t OFF_RED  = 168296448;  // u32 red[]

// ---------------- helpers ----------------
DEVI unsigned short f2bf(float x) {             // RNE f32 -> bf16
  unsigned u = __float_as_uint(x);
  return (unsigned short)((u + 0x7FFFu + ((u >> 16) & 1u)) >> 16);
}
DEVI float bf2f(short u) { return __uint_as_float(((unsigned)(unsigned short)u) << 16); }

DEVI void gload_lds16(const void* g, void* l) { // async global->LDS, 16B/lane
  __builtin_amdgcn_global_load_lds((const __attribute__((address_space(1))) unsigned int*)g,
                                   (__attribute__((address_space(3))) unsigned int*)l,
                                   16, 0, 0);
}
DEVI f32x4 mfma16(short8 a, short8 b, f32x4 c) {
  return __builtin_amdgcn_mfma_f32_16x16x32_bf16(a, b, c, 0, 0, 0);
}
DEVI float wave_max(float v) {
  #pragma unroll
  for (int o = 32; o; o >>= 1) v = fmaxf(v, __shfl_xor(v, o));
  return v;
}
DEVI float wave_sum(float v) {
  #pragma unroll
  for (int o = 32; o; o >>= 1) v += __shfl_xor(v, o);
  return v;
}
DEVI float clamp127(float x) { return fminf(fmaxf(x, -127.0f), 127.0f); }

// ---------------- K1: fp32 -> bf16 of hs + wq,wk,wv ----------------
__global__ __launch_bounds__(256) void convert_hqkv(
    const float* __restrict__ hs, const float* __restrict__ wq,
    const float* __restrict__ wk, const float* __restrict__ wv,
    unsigned short* __restrict__ hs_b, unsigned short* __restrict__ wqkv_b)
{
  const size_t NHS = 8388608ULL, WN = 16777216ULL;
  const size_t n4 = (NHS + 3 * WN) / 4;
  for (size_t i4 = (size_t)blockIdx.x * 256 + threadIdx.x; i4 < n4;
       i4 += (size_t)gridDim.x * 256) {
    size_t i = i4 * 4;
    const float* src; unsigned short* dst;
    if (i < NHS) { src = hs + i; dst = hs_b + i; }
    else {
      size_t j = i - NHS;
      src = (j < WN) ? (wq + j) : (j < 2 * WN) ? (wk + (j - WN)) : (wv + (j - 2 * WN));
      dst = wqkv_b + j;
    }
    float4 v = *(const float4*)src;
    unsigned long long p =
        (unsigned long long)f2bf(v.x) | ((unsigned long long)f2bf(v.y) << 16) |
        ((unsigned long long)f2bf(v.z) << 32) | ((unsigned long long)f2bf(v.w) << 48);
    *(unsigned long long*)dst = p;
  }
}

// ---------------- K1b: fp32 -> bf16 of wo (into dead qkv region) ----------------
__global__ __launch_bounds__(256) void convert_wo(
    const float* __restrict__ wo, unsigned short* __restrict__ wo_b)
{
  const size_t n4 = 16777216ULL / 4;
  for (size_t i4 = (size_t)blockIdx.x * 256 + threadIdx.x; i4 < n4;
       i4 += (size_t)gridDim.x * 256) {
    size_t i = i4 * 4;
    float4 v = *(const float4*)(wo + i);
    unsigned long long p =
        (unsigned long long)f2bf(v.x) | ((unsigned long long)f2bf(v.y) << 16) |
        ((unsigned long long)f2bf(v.z) << 32) | ((unsigned long long)f2bf(v.w) << 48);
    *(unsigned long long*)(wo_b + i) = p;
  }
}

// ---------------- K0: RoPE cos/sin table [1024][64] ----------------
__global__ void rope_table(float* __restrict__ ct, float* __restrict__ st) {
  int i = blockIdx.x * blockDim.x + threadIdx.x;
  if (i >= kS * 64) return;
  int s = i >> 6, j = i & 63;
  float invf = 1.0f / powf(10000.0f, (float)j / 64.0f);
  float fr = (float)s * invf;
  ct[i] = cosf(fr);
  st[i] = sinf(fr);
}

// ---------------- GEMM: C[M][N] = A[M][K]bf16 @ Bt[N][K]bf16; OUTBF: bf16 C ----------------
template <int OUTBF>
__global__ __launch_bounds__(256) void gemm_nt(
    const unsigned short* __restrict__ A, const unsigned short* __restrict__ Bt,
    void* __restrict__ Cv, int M, int N, int K,
    const unsigned* __restrict__ red, int redidx)
{
  __shared__ __align__(16) unsigned short As[128 * 64];
  __shared__ __align__(16) unsigned short Bs[128 * 64];
  const int tid = threadIdx.x, l = tid & 63, w = tid >> 6;
  const int m0 = blockIdx.y * 128, n0 = blockIdx.x * 128;
  const int wr = w >> 1, wc = w & 1;
  const int lrow = l >> 3, lsl = l & 7;
  const int srcks = lsl ^ lrow;        // pre-swizzled global k-slot (rule #21)
  f32x4 acc[4][4];
  #pragma unroll
  for (int a = 0; a < 4; ++a)
    #pragma unroll
    for (int b = 0; b < 4; ++b) { acc[a][b][0] = 0.f; acc[a][b][1] = 0.f; acc[a][b][2] = 0.f; acc[a][b][3] = 0.f; }

  for (int k0 = 0; k0 < K; k0 += 64) {
    #pragma unroll
    for (int j = 0; j < 4; ++j) {
      int c = w * 4 + j;
      int row = c * 8 + lrow;
      gload_lds16(A  + (size_t)(m0 + row) * K + k0 + srcks * 8, (char*)As + c * 1024);
      gload_lds16(Bt + (size_t)(n0 + row) * K + k0 + srcks * 8, (char*)Bs + c * 1024);
    }
    __syncthreads();
    #pragma unroll
    for (int kk = 0; kk < 2; ++kk) {
      short8 af[4], bf[4];
      #pragma unroll
      for (int mi = 0; mi < 4; ++mi) {
        int row = wr * 64 + mi * 16 + (l & 15);
        int slot = (kk * 4 + (l >> 4)) ^ (row & 7);
        af[mi] = *(const short8*)((const char*)As + row * 128 + slot * 16);
      }
      #pragma unroll
      for (int ni = 0; ni < 4; ++ni) {
        int row = wc * 64 + ni * 16 + (l & 15);
        int slot = (kk * 4 + (l >> 4)) ^ (row & 7);
        bf[ni] = *(const short8*)((const char*)Bs + row * 128 + slot * 16);
      }
      #pragma unroll
      for (int mi = 0; mi < 4; ++mi)
        #pragma unroll
        for (int ni = 0; ni < 4; ++ni)
          acc[mi][ni] = mfma16(af[mi], bf[ni], acc[mi][ni]);
    }
    __syncthreads();
  }

  float alpha = 1.0f;
  if (redidx >= 0) alpha = fmaxf(__uint_as_float(red[redidx]), 1e-8f) / 127.0f;
  #pragma unroll
  for (int mi = 0; mi < 4; ++mi) {
    int row = m0 + wr * 64 + mi * 16 + (l >> 4) * 4;
    #pragma unroll
    for (int ni = 0; ni < 4; ++ni) {
      int col = n0 + wc * 64 + ni * 16 + (l & 15);
      #pragma unroll
      for (int i = 0; i < 4; ++i) {
        float v = acc[mi][ni][i] * alpha;
        if constexpr (OUTBF) ((unsigned short*)Cv)[(size_t)(row + i) * N + col] = f2bf(v);
        else                 ((float*)Cv)[(size_t)(row + i) * N + col] = v;
      }
    }
  }
}

// ---------------- K3: read bf16 qkv, apply rope (no store), absmax q,k,v ----------------
__global__ __launch_bounds__(256) void rope_absmax(
    const unsigned short* __restrict__ qkv, const int* __restrict__ pos,
    const float* __restrict__ ct, const float* __restrict__ st,
    unsigned* __restrict__ red)
{
  int bs = blockIdx.x, t = threadIdx.x;
  int p = pos[bs];
  const unsigned short* row = qkv + (size_t)bs * 12288;
  int h = t >> 3, jc = (t & 7) * 8;
  float cs[8], sn[8];
  #pragma unroll
  for (int e = 0; e < 8; ++e) { cs[e] = ct[p * 64 + jc + e]; sn[e] = st[p * 64 + jc + e]; }
  float mq = 0.f, mk = 0.f, mv = 0.f;
  {
    short8 x1 = *(const short8*)(row + h * 128 + jc);
    short8 x2 = *(const short8*)(row + h * 128 + 64 + jc);
    #pragma unroll
    for (int e = 0; e < 8; ++e) {
      float a = bf2f(x1[e]), b = bf2f(x2[e]);
      mq = fmaxf(mq, fmaxf(fabsf(a * cs[e] - b * sn[e]), fabsf(b * cs[e] + a * sn[e])));
    }
  }
  {
    short8 x1 = *(const short8*)(row + 4096 + h * 128 + jc);
    short8 x2 = *(const short8*)(row + 4096 + h * 128 + 64 + jc);
    #pragma unroll
    for (int e = 0; e < 8; ++e) {
      float a = bf2f(x1[e]), b = bf2f(x2[e]);
      mk = fmaxf(mk, fmaxf(fabsf(a * cs[e] - b * sn[e]), fabsf(b * cs[e] + a * sn[e])));
    }
  }
  {
    short8 v0 = *(const short8*)(row + 8192 + t * 16);
    short8 v1 = *(const short8*)(row + 8192 + t * 16 + 8);
    #pragma unroll
    for (int e = 0; e < 8; ++e) mv = fmaxf(mv, fmaxf(fabsf(bf2f(v0[e])), fabsf(bf2f(v1[e]))));
  }
  mq = wave_max(mq); mk = wave_max(mk); mv = wave_max(mv);
  if ((t & 63) == 0) {
    atomicMax(red + 0, __float_as_uint(mq));
    atomicMax(red + 1, __float_as_uint(mk));
    atomicMax(red + 2, __float_as_uint(mv));
  }
}

// ---------------- K4: re-apply rope, quantize q,k -> [b][h][s][128] int-bf16 ----------------
__global__ __launch_bounds__(256) void quant_qk_rope(
    const unsigned short* __restrict__ qkv, const int* __restrict__ pos,
    const float* __restrict__ ct, const float* __restrict__ st,
    const unsigned* __restrict__ red,
    unsigned short* __restrict__ qq, unsigned short* __restrict__ kq)
{
  int bs = blockIdx.x, t = threadIdx.x;
  int b = bs >> 10, s = bs & 1023;
  int p = pos[bs];
  float iq = 127.0f / fmaxf(__uint_as_float(red[0]), 1e-8f);
  float ik = 127.0f / fmaxf(__uint_as_float(red[1]), 1e-8f);
  const unsigned short* row = qkv + (size_t)bs * 12288;
  int h = t >> 3, jc = (t & 7) * 8;
  float cs[8], sn[8];
  #pragma unroll
  for (int e = 0; e < 8; ++e) { cs[e] = ct[p * 64 + jc + e]; sn[e] = st[p * 64 + jc + e]; }
  size_t ob = ((size_t)(b * kH + h) * kS + s) * 128;
  {
    short8 x1 = *(const short8*)(row + h * 128 + jc);
    short8 x2 = *(const short8*)(row + h * 128 + 64 + jc);
    short8 o1, o2;
    #pragma unroll
    for (int e = 0; e < 8; ++e) {
      float a = bf2f(x1[e]), b2 = bf2f(x2[e]);
      o1[e] = (short)f2bf(clamp127(rintf((a * cs[e] - b2 * sn[e]) * iq)));
      o2[e] = (short)f2bf(clamp127(rintf((b2 * cs[e] + a * sn[e]) * iq)));
    }
    *(short8*)(qq + ob + jc) = o1;
    *(short8*)(qq + ob + 64 + jc) = o2;
  }
  {
    short8 x1 = *(const short8*)(row + 4096 + h * 128 + jc);
    short8 x2 = *(const short8*)(row + 4096 + h * 128 + 64 + jc);
    short8 o1, o2;
    #pragma unroll
    for (int e = 0; e < 8; ++e) {
      float a = bf2f(x1[e]), b2 = bf2f(x2[e]);
      o1[e] = (short)f2bf(clamp127(rintf((a * cs[e] - b2 * sn[e]) * ik)));
      o2[e] = (short)f2bf(clamp127(rintf((b2 * cs[e] + a * sn[e]) * ik)));
    }
    *(short8*)(kq + ob + jc) = o1;
    *(short8*)(kq + ob + 64 + jc) = o2;
  }
}

// ---------------- K5: quantize + transpose v -> [b*h][hd][s] int-bf16 ----------------
__global__ __launch_bounds__(256) void quantT_v(
    const unsigned short* __restrict__ qkv, const unsigned* __restrict__ red,
    unsigned short* __restrict__ vt)
{
  __shared__ float tile[32][132];
  int bh = blockIdx.x, st0 = blockIdx.y * 32;
  int b = bh >> 5, h = bh & 31;
  float iv = 127.0f / fmaxf(__uint_as_float(red[2]), 1e-8f);
  int t = threadIdx.x;
  #pragma unroll
  for (int e = 0; e < 2; ++e) {
    int idx = (e * 256 + t) * 8;
    int sl = idx >> 7, hd = idx & 127;
    short8 xv = *(const short8*)(qkv + (size_t)(b * 1024 + st0 + sl) * 12288 + 8192 + h * 128 + hd);
    #pragma unroll
    for (int q = 0; q < 8; ++q) tile[sl][hd + q] = clamp127(rintf(bf2f(xv[q]) * iv));
  }
  __syncthreads();
  #pragma unroll
  for (int e = 0; e < 16; ++e) {
    int idx = e * 256 + t;
    int sl = idx & 31, hd = idx >> 5;
    vt[((size_t)bh * 128 + hd) * kS + st0 + sl] = f2bf(tile[sl][hd]);
  }
}

// ---------------- K6: QK^T integer absmax, GEMM-structured (full matrix, pre-mask) ----------------
__global__ __launch_bounds__(256) void qk_absmax_gemm(
    const unsigned short* __restrict__ qq, const unsigned short* __restrict__ kq,
    unsigned* __restrict__ red)
{
  __shared__ __align__(16) unsigned short As[128 * 64];
  __shared__ __align__(16) unsigned short Bs[128 * 64];
  const int tid = threadIdx.x, l = tid & 63, w = tid >> 6;
  const int bh = blockIdx.z;
  const int m0 = blockIdx.y * 128, n0 = blockIdx.x * 128;
  const unsigned short* A  = qq + (size_t)bh * 131072;
  const unsigned short* Bt = kq + (size_t)bh * 131072;
  const int wr = w >> 1, wc = w & 1;
  const int lrow = l >> 3, lsl = l & 7;
  const int srcks = lsl ^ lrow;
  f32x4 acc[4][4];
  #pragma unroll
  for (int a = 0; a < 4; ++a)
    #pragma unroll
    for (int b = 0; b < 4; ++b) { acc[a][b][0] = 0.f; acc[a][b][1] = 0.f; acc[a][b][2] = 0.f; acc[a][b][3] = 0.f; }

  for (int k0 = 0; k0 < 128; k0 += 64) {
    #pragma unroll
    for (int j = 0; j < 4; ++j) {
      int c = w * 4 + j;
      int row = c * 8 + lrow;
      gload_lds16(A  + (size_t)(m0 + row) * 128 + k0 + srcks * 8, (char*)As + c * 1024);
      gload_lds16(Bt + (size_t)(n0 + row) * 128 + k0 + srcks * 8, (char*)Bs + c * 1024);
    }
    __syncthreads();
    #pragma unroll
    for (int kk = 0; kk < 2; ++kk) {
      short8 af[4], bf[4];
      #pragma unroll
      for (int mi = 0; mi < 4; ++mi) {
        int row = wr * 64 + mi * 16 + (l & 15);
        int slot = (kk * 4 + (l >> 4)) ^ (row & 7);
        af[mi] = *(const short8*)((const char*)As + row * 128 + slot * 16);
      }
      #pragma unroll
      for (int ni = 0; ni < 4; ++ni) {
        int row = wc * 64 + ni * 16 + (l & 15);
        int slot = (kk * 4 + (l >> 4)) ^ (row & 7);
        bf[ni] = *(const short8*)((const char*)Bs + row * 128 + slot * 16);
      }
      #pragma unroll
      for (int mi = 0; mi < 4; ++mi)
        #pragma unroll
        for (int ni = 0; ni < 4; ++ni)
          acc[mi][ni] = mfma16(af[mi], bf[ni], acc[mi][ni]);
    }
    __syncthreads();
  }

  float vmax = 0.f;
  #pragma unroll
  for (int mi = 0; mi < 4; ++mi)
    #pragma unroll
    for (int ni = 0; ni < 4; ++ni)
      #pragma unroll
      for (int i = 0; i < 4; ++i) vmax = fmaxf(vmax, fabsf(acc[mi][ni][i]));
  vmax = wave_max(vmax);
  __shared__ float sm[4];
  if (l == 0) sm[w] = vmax;
  __syncthreads();
  if (tid == 0)
    atomicMax(red + 3, __float_as_uint(fmaxf(fmaxf(sm[0], sm[1]), fmaxf(sm[2], sm[3]))));
}

// ---------------- K7: fused QK^T -> quant -> mask -> softmax -> quant -> PV (causal-skip) ----------------
__global__ __launch_bounds__(256) void softmax_pv(
    const unsigned short* __restrict__ qq, const unsigned short* __restrict__ kq,
    const unsigned short* __restrict__ vt,
    unsigned* __restrict__ red, float* __restrict__ ao)
{
  __shared__ unsigned short Lg[16][1024];   // 32 KB, int logits/probs as bf16, XOR-swizzled
  int bh = blockIdx.x, r0 = blockIdx.y * 16;
  int t = threadIdx.x, l = t & 63, w = t >> 6;
  float sq = fmaxf(__uint_as_float(red[0]), 1e-8f) / 127.0f;
  float sk = fmaxf(__uint_as_float(red[1]), 1e-8f) / 127.0f;
  const float c1 = sq * sk * kInvSqrtHD;           // int_dot -> attn_weight
  float sl = fmaxf(__uint_as_float(red[3]) * c1, 1e-8f) / 127.0f;
  float isl = 1.0f / sl;
  const unsigned short* qb = qq + (size_t)bh * 131072;
  const unsigned short* kb = kq + (size_t)bh * 131072;
  const unsigned short* vb = vt + (size_t)bh * 131072;
  const int ktop = r0 >> 4;                 // last key tile (contains diagonal)
  const int blimit = r0 + 16;               // cols >= blimit are prob-0

  // phase 1: QK^T (causal tiles only), quantize logits (int, bf16-exact), mask -> LDS
  short8 aq[4];
  #pragma unroll
  for (int s = 0; s < 4; ++s)
    aq[s] = *(const short8*)(qb + (size_t)(r0 + (l & 15)) * 128 + s * 32 + (l >> 4) * 8);
  for (int kt = w; kt <= ktop; kt += 4) {
    int key0 = kt * 16;
    short8 bq[4];
    #pragma unroll
    for (int s = 0; s < 4; ++s)
      bq[s] = *(const short8*)(kb + (size_t)(key0 + (l & 15)) * 128 + s * 32 + (l >> 4) * 8);
    f32x4 acc; acc[0] = 0.f; acc[1] = 0.f; acc[2] = 0.f; acc[3] = 0.f;
    #pragma unroll
    for (int s = 0; s < 4; ++s) acc = mfma16(aq[s], bq[s], acc);
    int col = key0 + (l & 15);
    #pragma unroll
    for (int i = 0; i < 4; ++i) {
      int rl = (l >> 4) * 4 + i;
      float qv = (col > r0 + rl) ? kMaskVal : clamp127(rintf(acc[i] * c1 * isl));
      Lg[rl][col ^ ((rl & 7) << 3)] = f2bf(qv);
    }
  }
  __syncthreads();

  // phase 2: per-row softmax on int logits + prob quantization (ints stored bf16)
  const int nch = (blimit + 511) >> 9;      // 512-col chunks (64 lanes x short8)
  #pragma unroll
  for (int r = 0; r < 4; ++r) {
    int row = w * 4 + r, xm = (row & 7) << 3;
    float vals[2][8];
    float m = kMaskVal;
    for (int j = 0; j < nch; ++j) {
      int base = j * 512 + l * 8;
      short8 v = *(const short8*)&Lg[row][base ^ xm];
      #pragma unroll
      for (int e = 0; e < 8; ++e) {
        float f = (base + e < blimit) ? bf2f(v[e]) : kMaskVal;
        vals[j][e] = f;
        m = fmaxf(m, f);
      }
    }
    m = wave_max(m);
    float sum = 0.f;
    float ex[2][8];
    for (int j = 0; j < nch; ++j)
      #pragma unroll
      for (int e = 0; e < 8; ++e) { ex[j][e] = __expf((vals[j][e] - m) * sl); sum += ex[j][e]; }
    sum = wave_sum(sum);
    float inv127 = 127.0f / sum;
    for (int j = 0; j < nch; ++j) {
      int base = j * 512 + l * 8;
      short8 o;
      #pragma unroll
      for (int e = 0; e < 8; ++e) o[e] = (short)f2bf(rintf(ex[j][e] * inv127));
      *(short8*)&Lg[row][base ^ xm] = o;
    }
  }
  __syncthreads();

  // phase 3: PV over causal k-slices — wave w owns hd tiles {2w, 2w+1}
  float sv = fmaxf(__uint_as_float(red[2]), 1e-8f) / 127.0f;
  const float c2 = sv * (1.0f / 127.0f);
  const int ksmax = (r0 + 47) >> 5;
  f32x4 pacc[2];
  pacc[0][0]=0.f;pacc[0][1]=0.f;pacc[0][2]=0.f;pacc[0][3]=0.f;
  pacc[1][0]=0.f;pacc[1][1]=0.f;pacc[1][2]=0.f;pacc[1][3]=0.f;
  for (int ks = 0; ks < ksmax; ++ks) {
    int r = l & 15, c0 = ks * 32 + (l >> 4) * 8;
    short8 af = *(const short8*)&Lg[r][c0 ^ ((r & 7) << 3)];
    #pragma unroll
    for (int j = 0; j < 2; ++j) {
      int hd = (w * 2 + j) * 16 + (l & 15);
      short8 bf = *(const short8*)(vb + (size_t)hd * kS + ks * 32 + (l >> 4) * 8);
      pacc[j] = mfma16(af, bf, pacc[j]);
    }
  }
  float vmax = 0.f;
  #pragma unroll
  for (int j = 0; j < 2; ++j) {
    int hd = (w * 2 + j) * 16 + (l & 15);
    int rbase = r0 + (l >> 4) * 4;
    #pragma unroll
    for (int i = 0; i < 4; ++i) {
      float val = pacc[j][i] * c2;
      ao[((size_t)bh * kS + rbase + i) * 128 + hd] = val;
      vmax = fmaxf(vmax, fabsf(val));
    }
  }
  vmax = wave_max(vmax);
  if (l == 0) atomicMax(red + 4, __float_as_uint(vmax));
}

// ---------------- K8: quantize attn_out -> int-bf16 [b][s][h*128+hd] ----------------
__global__ __launch_bounds__(256) void quant_ao(
    const float* __restrict__ ao, const unsigned* __restrict__ red,
    unsigned short* __restrict__ aob)
{
  float ia = 127.0f / fmaxf(__uint_as_float(red[4]), 1e-8f);
  const int n = 64 * kS * 128;
  for (int i = blockIdx.x * 256 + threadIdx.x; i < n; i += gridDim.x * 256) {
    int bh = i >> 17, rem = i & 131071;
    int s = rem >> 7, hd = rem & 127;
    int b = bh >> 5, h = bh & 31;
    aob[((size_t)(b * 1024 + s)) * 4096 + h * 128 + hd] = f2bf(clamp127(rintf(ao[i] * ia)));
  }
}

// ---------------- launch ----------------
extern "C" void kernel_launch(void* const* d_in, const int* in_sizes, int n_in,
                              void* d_out, int out_size, void* d_ws, size_t ws_size,
                              hipStream_t stream) {
  const float* hs = (const float*)d_in[0];
  const float* wq = (const float*)d_in[1];
  const float* wk = (const float*)d_in[2];
  const float* wv = (const float*)d_in[3];
  const float* wo = (const float*)d_in[4];
  const int* pos  = (const int*)d_in[5];
  char* ws = (char*)d_ws;

  unsigned short* hs_b   = (unsigned short*)(ws + OFF_A + A_HSB);
  unsigned short* wqkv_b = (unsigned short*)(ws + OFF_A + A_WQKV);
  unsigned short* qq     = (unsigned short*)(ws + OFF_A + A_QQ);
  unsigned short* kq     = (unsigned short*)(ws + OFF_A + A_KQ);
  unsigned short* vt     = (unsigned short*)(ws + OFF_A + A_VT);
  float*          ao     = (float*)(ws + OFF_A + A_AO);
  unsigned short* aob    = (unsigned short*)(ws + OFF_A + A_AOB);
  unsigned short* qkv    = (unsigned short*)(ws + OFF_QKV);
  unsigned short* wo_b   = (unsigned short*)(ws + OFF_QKV);   // after qkv is dead
  float*          rc     = (float*)(ws + OFF_TAB);
  float*          rs     = (float*)(ws + OFF_TAB + 262144);
  unsigned*       red    = (unsigned*)(ws + OFF_RED);

  (void)hipMemsetAsync(red, 0, 256, stream);

  rope_table<<<dim3(256), dim3(256), 0, stream>>>(rc, rs);
  convert_hqkv<<<dim3(2048), dim3(256), 0, stream>>>(hs, wq, wk, wv, hs_b, wqkv_b);
  gemm_nt<1><<<dim3(96, 16), dim3(256), 0, stream>>>(hs_b, wqkv_b, qkv, kM, 12288, 4096, red, -1);
  rope_absmax<<<dim3(2048), dim3(256), 0, stream>>>(qkv, pos, rc, rs, red);
  quant_qk_rope<<<dim3(2048), dim3(256), 0, stream>>>(qkv, pos, rc, rs, red, qq, kq);
  quantT_v<<<dim3(64, 32), dim3(256), 0, stream>>>(qkv, red, vt);
  convert_wo<<<dim3(1024), dim3(256), 0, stream>>>(wo, wo_b);
  qk_absmax_gemm<<<dim3(8, 8, 64), dim3(256), 0, stream>>>(qq, kq, red);
  softmax_pv<<<dim3(64, 64), dim3(256), 0, stream>>>(qq, kq, vt, red, ao);
  quant_ao<<<dim3(2048), dim3(256), 0, stream>>>(ao, red, aob);
  gemm_nt<0><<<dim3(32, 16), dim3(256), 0, stream>>>(aob, wo_b, d_out, kM, 4096, 4096, red, 4);
}

// Round 6
// 830.244 us; speedup vs baseline: 1.5750x; 1.4389x over previous
//
#include <hip/hip_runtime.h>
#include <cstdint>
#include <cstddef>

#define DEVI __device__ __forceinline__

typedef __attribute__((ext_vector_type(8))) short short8;
typedef __attribute__((ext_vector_type(4))) float f32x4;

static constexpr int kS = 1024, kH = 32;
static constexpr int kM = 2048;      // B*S
static constexpr float kInvSqrtHD = 0.08838834764831845f; // 1/sqrt(128)
static constexpr float kMaskVal = -3.0e38f;  // masked-logit marker

// ---------------- ws layout (bytes). Peak ~160.5 MB. ----------------
static constexpr size_t OFF_A    = 0;
static constexpr size_t A_HSB    = 0;          // bf16 [2048][4096]
static constexpr size_t A_WQKV   = 16777216;   // bf16 [12288][4096]
static constexpr size_t A_QQ     = 0;          // bf16(int) [64][1024][128]
static constexpr size_t A_KQ     = 16777216;   // bf16(int) [64][1024][128]
static constexpr size_t A_VT     = 33554432;   // bf16(int) [64][128][1024]
static constexpr size_t A_AO     = 50331648;   // f32 [64][1024][128]
static constexpr size_t A_AOB    = 83886080;   // bf16(int) [2048][4096]
static constexpr size_t OFF_QKV  = 117440512;  // bf16 [2048][12288] (48MB); later wo_b (32MB)
static constexpr size_t OFF_TAB  = 167772160;  // f32 cos[1024][64], sin[1024][64]
static constexpr size_t OFF_RED  = 168296448;  // u32 red[]

// ---------------- helpers ----------------
DEVI unsigned short f2bf(float x) {             // RNE f32 -> bf16
  unsigned u = __float_as_uint(x);
  return (unsigned short)((u + 0x7FFFu + ((u >> 16) & 1u)) >> 16);
}
DEVI float bf2f(short u) { return __uint_as_float(((unsigned)(unsigned short)u) << 16); }

DEVI void gload_lds16(const void* g, void* l) { // async global->LDS, 16B/lane
  __builtin_amdgcn_global_load_lds((const __attribute__((address_space(1))) unsigned int*)g,
                                   (__attribute__((address_space(3))) unsigned int*)l,
                                   16, 0, 0);
}
DEVI f32x4 mfma16(short8 a, short8 b, f32x4 c) {
  return __builtin_amdgcn_mfma_f32_16x16x32_bf16(a, b, c, 0, 0, 0);
}
DEVI float wave_max(float v) {
  #pragma unroll
  for (int o = 32; o; o >>= 1) v = fmaxf(v, __shfl_xor(v, o));
  return v;
}
DEVI float wave_sum(float v) {
  #pragma unroll
  for (int o = 32; o; o >>= 1) v += __shfl_xor(v, o);
  return v;
}
DEVI float clamp127(float x) { return fminf(fmaxf(x, -127.0f), 127.0f); }

// ---------------- K1: fp32 -> bf16 of hs + wq,wk,wv ----------------
__global__ __launch_bounds__(256) void convert_hqkv(
    const float* __restrict__ hs, const float* __restrict__ wq,
    const float* __restrict__ wk, const float* __restrict__ wv,
    unsigned short* __restrict__ hs_b, unsigned short* __restrict__ wqkv_b)
{
  const size_t NHS = 8388608ULL, WN = 16777216ULL;
  const size_t n4 = (NHS + 3 * WN) / 4;
  for (size_t i4 = (size_t)blockIdx.x * 256 + threadIdx.x; i4 < n4;
       i4 += (size_t)gridDim.x * 256) {
    size_t i = i4 * 4;
    const float* src; unsigned short* dst;
    if (i < NHS) { src = hs + i; dst = hs_b + i; }
    else {
      size_t j = i - NHS;
      src = (j < WN) ? (wq + j) : (j < 2 * WN) ? (wk + (j - WN)) : (wv + (j - 2 * WN));
      dst = wqkv_b + j;
    }
    float4 v = *(const float4*)src;
    unsigned long long p =
        (unsigned long long)f2bf(v.x) | ((unsigned long long)f2bf(v.y) << 16) |
        ((unsigned long long)f2bf(v.z) << 32) | ((unsigned long long)f2bf(v.w) << 48);
    *(unsigned long long*)dst = p;
  }
}

// ---------------- K1b: fp32 -> bf16 of wo (into dead qkv region) ----------------
__global__ __launch_bounds__(256) void convert_wo(
    const float* __restrict__ wo, unsigned short* __restrict__ wo_b)
{
  const size_t n4 = 16777216ULL / 4;
  for (size_t i4 = (size_t)blockIdx.x * 256 + threadIdx.x; i4 < n4;
       i4 += (size_t)gridDim.x * 256) {
    size_t i = i4 * 4;
    float4 v = *(const float4*)(wo + i);
    unsigned long long p =
        (unsigned long long)f2bf(v.x) | ((unsigned long long)f2bf(v.y) << 16) |
        ((unsigned long long)f2bf(v.z) << 32) | ((unsigned long long)f2bf(v.w) << 48);
    *(unsigned long long*)(wo_b + i) = p;
  }
}

// ---------------- K0: RoPE cos/sin table [1024][64] ----------------
__global__ void rope_table(float* __restrict__ ct, float* __restrict__ st) {
  int i = blockIdx.x * blockDim.x + threadIdx.x;
  if (i >= kS * 64) return;
  int s = i >> 6, j = i & 63;
  float invf = 1.0f / powf(10000.0f, (float)j / 64.0f);
  float fr = (float)s * invf;
  ct[i] = cosf(fr);
  st[i] = sinf(fr);
}

// ---------------- GEMM: C[M][N] = A[M][K]bf16 @ Bt[N][K]bf16; OUTBF: bf16 C ----------------
template <int OUTBF>
__global__ __launch_bounds__(256) void gemm_nt(
    const unsigned short* __restrict__ A, const unsigned short* __restrict__ Bt,
    void* __restrict__ Cv, int M, int N, int K,
    const unsigned* __restrict__ red, int redidx)
{
  __shared__ __align__(16) unsigned short As[128 * 64];
  __shared__ __align__(16) unsigned short Bs[128 * 64];
  const int tid = threadIdx.x, l = tid & 63, w = tid >> 6;
  const int m0 = blockIdx.y * 128, n0 = blockIdx.x * 128;
  const int wr = w >> 1, wc = w & 1;
  const int lrow = l >> 3, lsl = l & 7;
  const int srcks = lsl ^ lrow;        // pre-swizzled global k-slot (rule #21)
  f32x4 acc[4][4];
  #pragma unroll
  for (int a = 0; a < 4; ++a)
    #pragma unroll
    for (int b = 0; b < 4; ++b) { acc[a][b][0] = 0.f; acc[a][b][1] = 0.f; acc[a][b][2] = 0.f; acc[a][b][3] = 0.f; }

  for (int k0 = 0; k0 < K; k0 += 64) {
    #pragma unroll
    for (int j = 0; j < 4; ++j) {
      int c = w * 4 + j;
      int row = c * 8 + lrow;
      gload_lds16(A  + (size_t)(m0 + row) * K + k0 + srcks * 8, (char*)As + c * 1024);
      gload_lds16(Bt + (size_t)(n0 + row) * K + k0 + srcks * 8, (char*)Bs + c * 1024);
    }
    __syncthreads();
    #pragma unroll
    for (int kk = 0; kk < 2; ++kk) {
      short8 af[4], bf[4];
      #pragma unroll
      for (int mi = 0; mi < 4; ++mi) {
        int row = wr * 64 + mi * 16 + (l & 15);
        int slot = (kk * 4 + (l >> 4)) ^ (row & 7);
        af[mi] = *(const short8*)((const char*)As + row * 128 + slot * 16);
      }
      #pragma unroll
      for (int ni = 0; ni < 4; ++ni) {
        int row = wc * 64 + ni * 16 + (l & 15);
        int slot = (kk * 4 + (l >> 4)) ^ (row & 7);
        bf[ni] = *(const short8*)((const char*)Bs + row * 128 + slot * 16);
      }
      #pragma unroll
      for (int mi = 0; mi < 4; ++mi)
        #pragma unroll
        for (int ni = 0; ni < 4; ++ni)
          acc[mi][ni] = mfma16(af[mi], bf[ni], acc[mi][ni]);
    }
    __syncthreads();
  }

  float alpha = 1.0f;
  if (redidx >= 0) alpha = fmaxf(__uint_as_float(red[redidx]), 1e-8f) / 127.0f;
  #pragma unroll
  for (int mi = 0; mi < 4; ++mi) {
    int row = m0 + wr * 64 + mi * 16 + (l >> 4) * 4;
    #pragma unroll
    for (int ni = 0; ni < 4; ++ni) {
      int col = n0 + wc * 64 + ni * 16 + (l & 15);
      #pragma unroll
      for (int i = 0; i < 4; ++i) {
        float v = acc[mi][ni][i] * alpha;
        if constexpr (OUTBF) ((unsigned short*)Cv)[(size_t)(row + i) * N + col] = f2bf(v);
        else                 ((float*)Cv)[(size_t)(row + i) * N + col] = v;
      }
    }
  }
}

// ---------------- K3: rope (recompute, no store) + absmax q,k,v — low-atomic version ----------------
// 256 blocks x 8 rows each; 3 atomics per block (768 total, vs 24576 before).
__global__ __launch_bounds__(256) void rope_absmax(
    const unsigned short* __restrict__ qkv, const int* __restrict__ pos,
    const float* __restrict__ ct, const float* __restrict__ st,
    unsigned* __restrict__ red)
{
  int t = threadIdx.x;
  int h = t >> 3, jc = (t & 7) * 8;
  float mq = 0.f, mk = 0.f, mv = 0.f;
  for (int bs = blockIdx.x; bs < kM; bs += gridDim.x) {
    int p = pos[bs];
    const unsigned short* row = qkv + (size_t)bs * 12288;
    float cs[8], sn[8];
    #pragma unroll
    for (int e = 0; e < 8; ++e) { cs[e] = ct[p * 64 + jc + e]; sn[e] = st[p * 64 + jc + e]; }
    {
      short8 x1 = *(const short8*)(row + h * 128 + jc);
      short8 x2 = *(const short8*)(row + h * 128 + 64 + jc);
      #pragma unroll
      for (int e = 0; e < 8; ++e) {
        float a = bf2f(x1[e]), b = bf2f(x2[e]);
        mq = fmaxf(mq, fmaxf(fabsf(a * cs[e] - b * sn[e]), fabsf(b * cs[e] + a * sn[e])));
      }
    }
    {
      short8 x1 = *(const short8*)(row + 4096 + h * 128 + jc);
      short8 x2 = *(const short8*)(row + 4096 + h * 128 + 64 + jc);
      #pragma unroll
      for (int e = 0; e < 8; ++e) {
        float a = bf2f(x1[e]), b = bf2f(x2[e]);
        mk = fmaxf(mk, fmaxf(fabsf(a * cs[e] - b * sn[e]), fabsf(b * cs[e] + a * sn[e])));
      }
    }
    {
      short8 v0 = *(const short8*)(row + 8192 + t * 16);
      short8 v1 = *(const short8*)(row + 8192 + t * 16 + 8);
      #pragma unroll
      for (int e = 0; e < 8; ++e) mv = fmaxf(mv, fmaxf(fabsf(bf2f(v0[e])), fabsf(bf2f(v1[e]))));
    }
  }
  mq = wave_max(mq); mk = wave_max(mk); mv = wave_max(mv);
  __shared__ float sm[3][4];
  int w = t >> 6;
  if ((t & 63) == 0) { sm[0][w] = mq; sm[1][w] = mk; sm[2][w] = mv; }
  __syncthreads();
  if (t == 0) {
    atomicMax(red + 0, __float_as_uint(fmaxf(fmaxf(sm[0][0], sm[0][1]), fmaxf(sm[0][2], sm[0][3]))));
    atomicMax(red + 1, __float_as_uint(fmaxf(fmaxf(sm[1][0], sm[1][1]), fmaxf(sm[1][2], sm[1][3]))));
    atomicMax(red + 2, __float_as_uint(fmaxf(fmaxf(sm[2][0], sm[2][1]), fmaxf(sm[2][2], sm[2][3]))));
  }
}

// ---------------- K4: re-apply rope, quantize q,k -> [b][h][s][128] int-bf16 ----------------
__global__ __launch_bounds__(256) void quant_qk_rope(
    const unsigned short* __restrict__ qkv, const int* __restrict__ pos,
    const float* __restrict__ ct, const float* __restrict__ st,
    const unsigned* __restrict__ red,
    unsigned short* __restrict__ qq, unsigned short* __restrict__ kq)
{
  int bs = blockIdx.x, t = threadIdx.x;
  int b = bs >> 10, s = bs & 1023;
  int p = pos[bs];
  float iq = 127.0f / fmaxf(__uint_as_float(red[0]), 1e-8f);
  float ik = 127.0f / fmaxf(__uint_as_float(red[1]), 1e-8f);
  const unsigned short* row = qkv + (size_t)bs * 12288;
  int h = t >> 3, jc = (t & 7) * 8;
  float cs[8], sn[8];
  #pragma unroll
  for (int e = 0; e < 8; ++e) { cs[e] = ct[p * 64 + jc + e]; sn[e] = st[p * 64 + jc + e]; }
  size_t ob = ((size_t)(b * kH + h) * kS + s) * 128;
  {
    short8 x1 = *(const short8*)(row + h * 128 + jc);
    short8 x2 = *(const short8*)(row + h * 128 + 64 + jc);
    short8 o1, o2;
    #pragma unroll
    for (int e = 0; e < 8; ++e) {
      float a = bf2f(x1[e]), b2 = bf2f(x2[e]);
      o1[e] = (short)f2bf(clamp127(rintf((a * cs[e] - b2 * sn[e]) * iq)));
      o2[e] = (short)f2bf(clamp127(rintf((b2 * cs[e] + a * sn[e]) * iq)));
    }
    *(short8*)(qq + ob + jc) = o1;
    *(short8*)(qq + ob + 64 + jc) = o2;
  }
  {
    short8 x1 = *(const short8*)(row + 4096 + h * 128 + jc);
    short8 x2 = *(const short8*)(row + 4096 + h * 128 + 64 + jc);
    short8 o1, o2;
    #pragma unroll
    for (int e = 0; e < 8; ++e) {
      float a = bf2f(x1[e]), b2 = bf2f(x2[e]);
      o1[e] = (short)f2bf(clamp127(rintf((a * cs[e] - b2 * sn[e]) * ik)));
      o2[e] = (short)f2bf(clamp127(rintf((b2 * cs[e] + a * sn[e]) * ik)));
    }
    *(short8*)(kq + ob + jc) = o1;
    *(short8*)(kq + ob + 64 + jc) = o2;
  }
}

// ---------------- K5: quantize + transpose v -> [b*h][hd][s] int-bf16 ----------------
__global__ __launch_bounds__(256) void quantT_v(
    const unsigned short* __restrict__ qkv, const unsigned* __restrict__ red,
    unsigned short* __restrict__ vt)
{
  __shared__ float tile[32][132];
  int bh = blockIdx.x, st0 = blockIdx.y * 32;
  int b = bh >> 5, h = bh & 31;
  float iv = 127.0f / fmaxf(__uint_as_float(red[2]), 1e-8f);
  int t = threadIdx.x;
  #pragma unroll
  for (int e = 0; e < 2; ++e) {
    int idx = (e * 256 + t) * 8;
    int sl = idx >> 7, hd = idx & 127;
    short8 xv = *(const short8*)(qkv + (size_t)(b * 1024 + st0 + sl) * 12288 + 8192 + h * 128 + hd);
    #pragma unroll
    for (int q = 0; q < 8; ++q) tile[sl][hd + q] = clamp127(rintf(bf2f(xv[q]) * iv));
  }
  __syncthreads();
  #pragma unroll
  for (int e = 0; e < 16; ++e) {
    int idx = e * 256 + t;
    int sl = idx & 31, hd = idx >> 5;
    vt[((size_t)bh * 128 + hd) * kS + st0 + sl] = f2bf(tile[sl][hd]);
  }
}

// ---------------- K6: QK^T integer absmax, GEMM-structured ----------------
__global__ __launch_bounds__(256) void qk_absmax_gemm(
    const unsigned short* __restrict__ qq, const unsigned short* __restrict__ kq,
    unsigned* __restrict__ red)
{
  __shared__ __align__(16) unsigned short As[128 * 64];
  __shared__ __align__(16) unsigned short Bs[128 * 64];
  const int tid = threadIdx.x, l = tid & 63, w = tid >> 6;
  const int bh = blockIdx.z;
  const int m0 = blockIdx.y * 128, n0 = blockIdx.x * 128;
  const unsigned short* A  = qq + (size_t)bh * 131072;
  const unsigned short* Bt = kq + (size_t)bh * 131072;
  const int wr = w >> 1, wc = w & 1;
  const int lrow = l >> 3, lsl = l & 7;
  const int srcks = lsl ^ lrow;
  f32x4 acc[4][4];
  #pragma unroll
  for (int a = 0; a < 4; ++a)
    #pragma unroll
    for (int b = 0; b < 4; ++b) { acc[a][b][0] = 0.f; acc[a][b][1] = 0.f; acc[a][b][2] = 0.f; acc[a][b][3] = 0.f; }

  for (int k0 = 0; k0 < 128; k0 += 64) {
    #pragma unroll
    for (int j = 0; j < 4; ++j) {
      int c = w * 4 + j;
      int row = c * 8 + lrow;
      gload_lds16(A  + (size_t)(m0 + row) * 128 + k0 + srcks * 8, (char*)As + c * 1024);
      gload_lds16(Bt + (size_t)(n0 + row) * 128 + k0 + srcks * 8, (char*)Bs + c * 1024);
    }
    __syncthreads();
    #pragma unroll
    for (int kk = 0; kk < 2; ++kk) {
      short8 af[4], bf[4];
      #pragma unroll
      for (int mi = 0; mi < 4; ++mi) {
        int row = wr * 64 + mi * 16 + (l & 15);
        int slot = (kk * 4 + (l >> 4)) ^ (row & 7);
        af[mi] = *(const short8*)((const char*)As + row * 128 + slot * 16);
      }
      #pragma unroll
      for (int ni = 0; ni < 4; ++ni) {
        int row = wc * 64 + ni * 16 + (l & 15);
        int slot = (kk * 4 + (l >> 4)) ^ (row & 7);
        bf[ni] = *(const short8*)((const char*)Bs + row * 128 + slot * 16);
      }
      #pragma unroll
      for (int mi = 0; mi < 4; ++mi)
        #pragma unroll
        for (int ni = 0; ni < 4; ++ni)
          acc[mi][ni] = mfma16(af[mi], bf[ni], acc[mi][ni]);
    }
    __syncthreads();
  }

  float vmax = 0.f;
  #pragma unroll
  for (int mi = 0; mi < 4; ++mi)
    #pragma unroll
    for (int ni = 0; ni < 4; ++ni)
      #pragma unroll
      for (int i = 0; i < 4; ++i) vmax = fmaxf(vmax, fabsf(acc[mi][ni][i]));
  vmax = wave_max(vmax);
  __shared__ float sm[4];
  if (l == 0) sm[w] = vmax;
  __syncthreads();
  if (tid == 0)
    atomicMax(red + 3, __float_as_uint(fmaxf(fmaxf(sm[0], sm[1]), fmaxf(sm[2], sm[3]))));
}

// ---------------- K7: fused QK^T -> quant -> mask -> softmax -> quant -> PV (causal-skip) ----------------
__global__ __launch_bounds__(256) void softmax_pv(
    const unsigned short* __restrict__ qq, const unsigned short* __restrict__ kq,
    const unsigned short* __restrict__ vt,
    unsigned* __restrict__ red, float* __restrict__ ao)
{
  __shared__ unsigned short Lg[16][1024];   // 32 KB, int logits/probs as bf16, XOR-swizzled
  int bh = blockIdx.x, r0 = blockIdx.y * 16;
  int t = threadIdx.x, l = t & 63, w = t >> 6;
  float sq = fmaxf(__uint_as_float(red[0]), 1e-8f) / 127.0f;
  float sk = fmaxf(__uint_as_float(red[1]), 1e-8f) / 127.0f;
  const float c1 = sq * sk * kInvSqrtHD;           // int_dot -> attn_weight
  float sl = fmaxf(__uint_as_float(red[3]) * c1, 1e-8f) / 127.0f;
  float isl = 1.0f / sl;
  const unsigned short* qb = qq + (size_t)bh * 131072;
  const unsigned short* kb = kq + (size_t)bh * 131072;
  const unsigned short* vb = vt + (size_t)bh * 131072;
  const int ktop = r0 >> 4;                 // last key tile (contains diagonal)
  const int blimit = r0 + 16;               // cols >= blimit are prob-0

  // phase 1: QK^T (causal tiles only), quantize logits, mask -> LDS
  short8 aq[4];
  #pragma unroll
  for (int s = 0; s < 4; ++s)
    aq[s] = *(const short8*)(qb + (size_t)(r0 + (l & 15)) * 128 + s * 32 + (l >> 4) * 8);
  for (int kt = w; kt <= ktop; kt += 4) {
    int key0 = kt * 16;
    short8 bq[4];
    #pragma unroll
    for (int s = 0; s < 4; ++s)
      bq[s] = *(const short8*)(kb + (size_t)(key0 + (l & 15)) * 128 + s * 32 + (l >> 4) * 8);
    f32x4 acc; acc[0] = 0.f; acc[1] = 0.f; acc[2] = 0.f; acc[3] = 0.f;
    #pragma unroll
    for (int s = 0; s < 4; ++s) acc = mfma16(aq[s], bq[s], acc);
    int col = key0 + (l & 15);
    #pragma unroll
    for (int i = 0; i < 4; ++i) {
      int rl = (l >> 4) * 4 + i;
      float qv = (col > r0 + rl) ? kMaskVal : clamp127(rintf(acc[i] * c1 * isl));
      Lg[rl][col ^ ((rl & 7) << 3)] = f2bf(qv);
    }
  }
  __syncthreads();

  // phase 2: per-row softmax on int logits + prob quantization (ints stored bf16)
  const int nch = (blimit + 511) >> 9;      // 512-col chunks (64 lanes x short8)
  #pragma unroll
  for (int r = 0; r < 4; ++r) {
    int row = w * 4 + r, xm = (row & 7) << 3;
    float vals[2][8];
    float m = kMaskVal;
    for (int j = 0; j < nch; ++j) {
      int base = j * 512 + l * 8;
      short8 v = *(const short8*)&Lg[row][base ^ xm];
      #pragma unroll
      for (int e = 0; e < 8; ++e) {
        float f = (base + e < blimit) ? bf2f(v[e]) : kMaskVal;
        vals[j][e] = f;
        m = fmaxf(m, f);
      }
    }
    m = wave_max(m);
    float sum = 0.f;
    float ex[2][8];
    for (int j = 0; j < nch; ++j)
      #pragma unroll
      for (int e = 0; e < 8; ++e) { ex[j][e] = __expf((vals[j][e] - m) * sl); sum += ex[j][e]; }
    sum = wave_sum(sum);
    float inv127 = 127.0f / sum;
    for (int j = 0; j < nch; ++j) {
      int base = j * 512 + l * 8;
      short8 o;
      #pragma unroll
      for (int e = 0; e < 8; ++e) o[e] = (short)f2bf(rintf(ex[j][e] * inv127));
      *(short8*)&Lg[row][base ^ xm] = o;
    }
  }
  __syncthreads();

  // phase 3: PV over causal k-slices — wave w owns hd tiles {2w, 2w+1}
  float sv = fmaxf(__uint_as_float(red[2]), 1e-8f) / 127.0f;
  const float c2 = sv * (1.0f / 127.0f);
  const int ksmax = (r0 + 47) >> 5;
  f32x4 pacc[2];
  pacc[0][0]=0.f;pacc[0][1]=0.f;pacc[0][2]=0.f;pacc[0][3]=0.f;
  pacc[1][0]=0.f;pacc[1][1]=0.f;pacc[1][2]=0.f;pacc[1][3]=0.f;
  for (int ks = 0; ks < ksmax; ++ks) {
    int r = l & 15, c0 = ks * 32 + (l >> 4) * 8;
    short8 af = *(const short8*)&Lg[r][c0 ^ ((r & 7) << 3)];
    #pragma unroll
    for (int j = 0; j < 2; ++j) {
      int hd = (w * 2 + j) * 16 + (l & 15);
      short8 bf = *(const short8*)(vb + (size_t)hd * kS + ks * 32 + (l >> 4) * 8);
      pacc[j] = mfma16(af, bf, pacc[j]);
    }
  }
  float vmax = 0.f;
  #pragma unroll
  for (int j = 0; j < 2; ++j) {
    int hd = (w * 2 + j) * 16 + (l & 15);
    int rbase = r0 + (l >> 4) * 4;
    #pragma unroll
    for (int i = 0; i < 4; ++i) {
      float val = pacc[j][i] * c2;
      ao[((size_t)bh * kS + rbase + i) * 128 + hd] = val;
      vmax = fmaxf(vmax, fabsf(val));
    }
  }
  vmax = wave_max(vmax);
  __shared__ float sm2[4];
  if (l == 0) sm2[w] = vmax;
  __syncthreads();
  if (t == 0)
    atomicMax(red + 4, __float_as_uint(fmaxf(fmaxf(sm2[0], sm2[1]), fmaxf(sm2[2], sm2[3]))));
}

// ---------------- K8: quantize attn_out -> int-bf16 [b][s][h*128+hd] ----------------
__global__ __launch_bounds__(256) void quant_ao(
    const float* __restrict__ ao, const unsigned* __restrict__ red,
    unsigned short* __restrict__ aob)
{
  float ia = 127.0f / fmaxf(__uint_as_float(red[4]), 1e-8f);
  const int n = 64 * kS * 128;
  for (int i = blockIdx.x * 256 + threadIdx.x; i < n; i += gridDim.x * 256) {
    int bh = i >> 17, rem = i & 131071;
    int s = rem >> 7, hd = rem & 127;
    int b = bh >> 5, h = bh & 31;
    aob[((size_t)(b * 1024 + s)) * 4096 + h * 128 + hd] = f2bf(clamp127(rintf(ao[i] * ia)));
  }
}

// ---------------- launch ----------------
extern "C" void kernel_launch(void* const* d_in, const int* in_sizes, int n_in,
                              void* d_out, int out_size, void* d_ws, size_t ws_size,
                              hipStream_t stream) {
  const float* hs = (const float*)d_in[0];
  const float* wq = (const float*)d_in[1];
  const float* wk = (const float*)d_in[2];
  const float* wv = (const float*)d_in[3];
  const float* wo = (const float*)d_in[4];
  const int* pos  = (const int*)d_in[5];
  char* ws = (char*)d_ws;

  unsigned short* hs_b   = (unsigned short*)(ws + OFF_A + A_HSB);
  unsigned short* wqkv_b = (unsigned short*)(ws + OFF_A + A_WQKV);
  unsigned short* qq     = (unsigned short*)(ws + OFF_A + A_QQ);
  unsigned short* kq     = (unsigned short*)(ws + OFF_A + A_KQ);
  unsigned short* vt     = (unsigned short*)(ws + OFF_A + A_VT);
  float*          ao     = (float*)(ws + OFF_A + A_AO);
  unsigned short* aob    = (unsigned short*)(ws + OFF_A + A_AOB);
  unsigned short* qkv    = (unsigned short*)(ws + OFF_QKV);
  unsigned short* wo_b   = (unsigned short*)(ws + OFF_QKV);   // after qkv is dead
  float*          rc     = (float*)(ws + OFF_TAB);
  float*          rs     = (float*)(ws + OFF_TAB + 262144);
  unsigned*       red    = (unsigned*)(ws + OFF_RED);

  (void)hipMemsetAsync(red, 0, 256, stream);

  rope_table<<<dim3(256), dim3(256), 0, stream>>>(rc, rs);
  convert_hqkv<<<dim3(2048), dim3(256), 0, stream>>>(hs, wq, wk, wv, hs_b, wqkv_b);
  gemm_nt<1><<<dim3(96, 16), dim3(256), 0, stream>>>(hs_b, wqkv_b, qkv, kM, 12288, 4096, red, -1);
  rope_absmax<<<dim3(256), dim3(256), 0, stream>>>(qkv, pos, rc, rs, red);
  quant_qk_rope<<<dim3(2048), dim3(256), 0, stream>>>(qkv, pos, rc, rs, red, qq, kq);
  quantT_v<<<dim3(64, 32), dim3(256), 0, stream>>>(qkv, red, vt);
  convert_wo<<<dim3(1024), dim3(256), 0, stream>>>(wo, wo_b);
  qk_absmax_gemm<<<dim3(8, 8, 64), dim3(256), 0, stream>>>(qq, kq, red);
  softmax_pv<<<dim3(64, 64), dim3(256), 0, stream>>>(qq, kq, vt, red, ao);
  quant_ao<<<dim3(2048), dim3(256), 0, stream>>>(ao, red, aob);
  gemm_nt<0><<<dim3(32, 16), dim3(256), 0, stream>>>(aob, wo_b, d_out, kM, 4096, 4096, red, 4);
}

// Round 8
// 811.939 us; speedup vs baseline: 1.6105x; 1.0225x over previous
//
#include <hip/hip_runtime.h>
#include <cstdint>
#include <cstddef>

#define DEVI __device__ __forceinline__

typedef __attribute__((ext_vector_type(8))) short short8;
typedef __attribute__((ext_vector_type(4))) float f32x4;

static constexpr int kS = 1024, kH = 32;
static constexpr int kM = 2048;      // B*S
static constexpr float kInvSqrtHD = 0.08838834764831845f; // 1/sqrt(128)
static constexpr float kMaskVal = -3.0e38f;  // masked-logit marker

// ---------------- ws layout (bytes). Peak ~160.5 MB. ----------------
static constexpr size_t OFF_A    = 0;
static constexpr size_t A_HSB    = 0;          // bf16 [2048][4096]
static constexpr size_t A_WQKV   = 16777216;   // bf16 [12288][4096]
static constexpr size_t A_QQ     = 0;          // bf16(int) [64][1024][128]
static constexpr size_t A_KQ     = 16777216;   // bf16(int) [64][1024][128]
static constexpr size_t A_VT     = 33554432;   // bf16(int) [64][128][1024]
static constexpr size_t A_AO     = 50331648;   // f32 [64][1024][128]
static constexpr size_t A_AOB    = 83886080;   // bf16(int) [2048][4096]
static constexpr size_t OFF_QKV  = 117440512;  // bf16 [2048][12288] (48MB); later wo_b (32MB)
static constexpr size_t OFF_TAB  = 167772160;  // f32 cos[1024][64], sin[1024][64]
static constexpr size_t OFF_RED  = 168296448;  // u32 red[]

// ---------------- helpers ----------------
DEVI unsigned short f2bf(float x) {             // RNE f32 -> bf16
  unsigned u = __float_as_uint(x);
  return (unsigned short)((u + 0x7FFFu + ((u >> 16) & 1u)) >> 16);
}
DEVI float bf2f(short u) { return __uint_as_float(((unsigned)(unsigned short)u) << 16); }

DEVI void gload_lds16(const void* g, void* l) { // async global->LDS, 16B/lane
  __builtin_amdgcn_global_load_lds((const __attribute__((address_space(1))) unsigned int*)g,
                                   (__attribute__((address_space(3))) unsigned int*)l,
                                   16, 0, 0);
}
DEVI f32x4 mfma16(short8 a, short8 b, f32x4 c) {
  return __builtin_amdgcn_mfma_f32_16x16x32_bf16(a, b, c, 0, 0, 0);
}
DEVI float wave_max(float v) {
  #pragma unroll
  for (int o = 32; o; o >>= 1) v = fmaxf(v, __shfl_xor(v, o));
  return v;
}
DEVI float wave_sum(float v) {
  #pragma unroll
  for (int o = 32; o; o >>= 1) v += __shfl_xor(v, o);
  return v;
}
DEVI float clamp127(float x) { return fminf(fmaxf(x, -127.0f), 127.0f); }

// ---------------- K1: fp32 -> bf16 of hs + wq,wk,wv ----------------
__global__ __launch_bounds__(256) void convert_hqkv(
    const float* __restrict__ hs, const float* __restrict__ wq,
    const float* __restrict__ wk, const float* __restrict__ wv,
    unsigned short* __restrict__ hs_b, unsigned short* __restrict__ wqkv_b)
{
  const size_t NHS = 8388608ULL, WN = 16777216ULL;
  const size_t n4 = (NHS + 3 * WN) / 4;
  for (size_t i4 = (size_t)blockIdx.x * 256 + threadIdx.x; i4 < n4;
       i4 += (size_t)gridDim.x * 256) {
    size_t i = i4 * 4;
    const float* src; unsigned short* dst;
    if (i < NHS) { src = hs + i; dst = hs_b + i; }
    else {
      size_t j = i - NHS;
      src = (j < WN) ? (wq + j) : (j < 2 * WN) ? (wk + (j - WN)) : (wv + (j - 2 * WN));
      dst = wqkv_b + j;
    }
    float4 v = *(const float4*)src;
    unsigned long long p =
        (unsigned long long)f2bf(v.x) | ((unsigned long long)f2bf(v.y) << 16) |
        ((unsigned long long)f2bf(v.z) << 32) | ((unsigned long long)f2bf(v.w) << 48);
    *(unsigned long long*)dst = p;
  }
}

// ---------------- K1b: fp32 -> bf16 of wo (into dead qkv region) ----------------
__global__ __launch_bounds__(256) void convert_wo(
    const float* __restrict__ wo, unsigned short* __restrict__ wo_b)
{
  const size_t n4 = 16777216ULL / 4;
  for (size_t i4 = (size_t)blockIdx.x * 256 + threadIdx.x; i4 < n4;
       i4 += (size_t)gridDim.x * 256) {
    size_t i = i4 * 4;
    float4 v = *(const float4*)(wo + i);
    unsigned long long p =
        (unsigned long long)f2bf(v.x) | ((unsigned long long)f2bf(v.y) << 16) |
        ((unsigned long long)f2bf(v.z) << 32) | ((unsigned long long)f2bf(v.w) << 48);
    *(unsigned long long*)(wo_b + i) = p;
  }
}

// ---------------- K0: RoPE cos/sin table [1024][64] ----------------
__global__ void rope_table(float* __restrict__ ct, float* __restrict__ st) {
  int i = blockIdx.x * blockDim.x + threadIdx.x;
  if (i >= kS * 64) return;
  int s = i >> 6, j = i & 63;
  float invf = 1.0f / powf(10000.0f, (float)j / 64.0f);
  float fr = (float)s * invf;
  ct[i] = cosf(fr);
  st[i] = sinf(fr);
}

// ================= 8-phase 256x256 GEMM (T2+T3+T4+T5) =================
// C[M][N] = A[M][K] @ Bt[N][K], bf16 in, counted-vmcnt pipeline.
// LDS: L[dbuf][mat][khalf][256][32] bf16 = 128 KB. k-half = staging unit (16 KB).
// Swizzle: 16B slot ss = s ^ ((row>>1)&3)  (2-way bank alias = free).
// Fences: vmcnt(4)+barrier at end of ph1/ph3 — never a full drain in steady state.
DEVI void stage_half256(const unsigned short* __restrict__ Mat, int rowbase, int K,
                        int kcol, unsigned short* lbase, int w, int l)
{
  int c = 2 * w;
  int r = c * 16 + (l >> 2);
  int s = ((l & 3) ^ ((r >> 1) & 3)) * 8;     // pre-swizzled global k-slot
  gload_lds16(Mat + (size_t)(rowbase + r) * K + kcol + s, lbase + c * 512);
  int r2 = r + 16;                             // (r2>>1)&3 == (r>>1)&3
  gload_lds16(Mat + (size_t)(rowbase + r2) * K + kcol + s, lbase + (c + 1) * 512);
}

DEVI short8 frag256(const unsigned short* khbuf, int r, int l) {
  int ss = (l >> 4) ^ ((r >> 1) & 3);
  return *(const short8*)(khbuf + r * 32 + ss * 8);
}

template <int OUTBF>
__global__ __launch_bounds__(512, 2) void gemm_nt8(
    const unsigned short* __restrict__ A, const unsigned short* __restrict__ Bt,
    void* __restrict__ Cv, int M, int N, int K,
    const unsigned* __restrict__ red, int redidx)
{
  __shared__ __align__(16) unsigned short L[2][2][2][256 * 32];  // [dbuf][A/B][kh][r][c]
  const int tid = threadIdx.x, l = tid & 63, w = tid >> 6;
  const int wr = w >> 2, wc = w & 3;           // 2x4 wave grid; per-wave C = 128x64
  const int m0 = blockIdx.y * 256, n0 = blockIdx.x * 256;
  const int NT = K >> 6;

  f32x4 acc[8][4];
  #pragma unroll
  for (int x = 0; x < 8; ++x)
    #pragma unroll
    for (int y = 0; y < 4; ++y) { acc[x][y][0]=0.f; acc[x][y][1]=0.f; acc[x][y][2]=0.f; acc[x][y][3]=0.f; }

  // prologue: stage tile 0 (4 k-halves), wait for the first two.
  stage_half256(A,  m0, K, 0,  &L[0][0][0][0], w, l);
  stage_half256(Bt, n0, K, 0,  &L[0][1][0][0], w, l);
  stage_half256(A,  m0, K, 32, &L[0][0][1][0], w, l);
  stage_half256(Bt, n0, K, 32, &L[0][1][1][0], w, l);
  asm volatile("s_waitcnt vmcnt(4)" ::: "memory");
  __builtin_amdgcn_s_barrier();

  int d = 0;
  for (int t = 0; t < NT; ++t) {
    const int last = (t == NT - 1);
    const int nd = d ^ 1;
    const int k1 = (t + 1) << 6;
    short8 a[4], b[4];

    // ---- ph0: frags mi0-3 x kh0 ----
    {
      const unsigned short* Ab = &L[d][0][0][0];
      const unsigned short* Bb = &L[d][1][0][0];
      #pragma unroll
      for (int i = 0; i < 4; ++i) a[i] = frag256(Ab, wr * 128 + i * 16 + (l & 15), l);
      #pragma unroll
      for (int i = 0; i < 4; ++i) b[i] = frag256(Bb, wc * 64 + i * 16 + (l & 15), l);
    }
    if (!last) stage_half256(A, m0, K, k1, &L[nd][0][0][0], w, l);
    __builtin_amdgcn_s_barrier();
    asm volatile("s_waitcnt lgkmcnt(0)" ::: "memory");
    __builtin_amdgcn_sched_barrier(0);
    __builtin_amdgcn_s_setprio(1);
    #pragma unroll
    for (int i = 0; i < 4; ++i)
      #pragma unroll
      for (int j = 0; j < 4; ++j) acc[i][j] = mfma16(a[i], b[j], acc[i][j]);
    __builtin_amdgcn_s_setprio(0);
    __builtin_amdgcn_s_barrier();

    // ---- ph1: frags mi4-7 x kh0 (reuse b) ----
    {
      const unsigned short* Ab = &L[d][0][0][0];
      #pragma unroll
      for (int i = 0; i < 4; ++i) a[i] = frag256(Ab, wr * 128 + (4 + i) * 16 + (l & 15), l);
    }
    if (!last) stage_half256(Bt, n0, K, k1, &L[nd][1][0][0], w, l);
    __builtin_amdgcn_s_barrier();
    asm volatile("s_waitcnt lgkmcnt(0)" ::: "memory");
    __builtin_amdgcn_sched_barrier(0);
    __builtin_amdgcn_s_setprio(1);
    #pragma unroll
    for (int i = 0; i < 4; ++i)
      #pragma unroll
      for (int j = 0; j < 4; ++j) acc[4 + i][j] = mfma16(a[i], b[j], acc[4 + i][j]);
    __builtin_amdgcn_s_setprio(0);
    if (!last) asm volatile("s_waitcnt vmcnt(4)" ::: "memory");  // own kh1 halves landed
    else       asm volatile("s_waitcnt vmcnt(0)" ::: "memory");
    __builtin_amdgcn_s_barrier();

    // ---- ph2: frags mi0-3 x kh1 ----
    {
      const unsigned short* Ab = &L[d][0][1][0];
      const unsigned short* Bb = &L[d][1][1][0];
      #pragma unroll
      for (int i = 0; i < 4; ++i) a[i] = frag256(Ab, wr * 128 + i * 16 + (l & 15), l);
      #pragma unroll
      for (int i = 0; i < 4; ++i) b[i] = frag256(Bb, wc * 64 + i * 16 + (l & 15), l);
    }
    if (!last) stage_half256(A, m0, K, k1 + 32, &L[nd][0][1][0], w, l);
    __builtin_amdgcn_s_barrier();
    asm volatile("s_waitcnt lgkmcnt(0)" ::: "memory");
    __builtin_amdgcn_sched_barrier(0);
    __builtin_amdgcn_s_setprio(1);
    #pragma unroll
    for (int i = 0; i < 4; ++i)
      #pragma unroll
      for (int j = 0; j < 4; ++j) acc[i][j] = mfma16(a[i], b[j], acc[i][j]);
    __builtin_amdgcn_s_setprio(0);
    __builtin_amdgcn_s_barrier();

    // ---- ph3: frags mi4-7 x kh1 ----
    {
      const unsigned short* Ab = &L[d][0][1][0];
      #pragma unroll
      for (int i = 0; i < 4; ++i) a[i] = frag256(Ab, wr * 128 + (4 + i) * 16 + (l & 15), l);
    }
    if (!last) stage_half256(Bt, n0, K, k1 + 32, &L[nd][1][1][0], w, l);
    __builtin_amdgcn_s_barrier();
    asm volatile("s_waitcnt lgkmcnt(0)" ::: "memory");
    __builtin_amdgcn_sched_barrier(0);
    __builtin_amdgcn_s_setprio(1);
    #pragma unroll
    for (int i = 0; i < 4; ++i)
      #pragma unroll
      for (int j = 0; j < 4; ++j) acc[4 + i][j] = mfma16(a[i], b[j], acc[4 + i][j]);
    __builtin_amdgcn_s_setprio(0);
    if (!last) asm volatile("s_waitcnt vmcnt(4)" ::: "memory");  // next tile's kh0 halves landed
    __builtin_amdgcn_s_barrier();

    d = nd;
  }

  float alpha = 1.0f;
  if (redidx >= 0) alpha = fmaxf(__uint_as_float(red[redidx]), 1e-8f) / 127.0f;
  #pragma unroll
  for (int mi = 0; mi < 8; ++mi) {
    int row = m0 + wr * 128 + mi * 16 + (l >> 4) * 4;
    #pragma unroll
    for (int ni = 0; ni < 4; ++ni) {
      int col = n0 + wc * 64 + ni * 16 + (l & 15);
      #pragma unroll
      for (int i = 0; i < 4; ++i) {
        float v = acc[mi][ni][i] * alpha;
        if constexpr (OUTBF) ((unsigned short*)Cv)[(size_t)(row + i) * N + col] = f2bf(v);
        else                 ((float*)Cv)[(size_t)(row + i) * N + col] = v;
      }
    }
  }
}

// ---------------- GEMM (128^2, 2-phase) — kept for WO (grid too small for 256^2) ----------------
template <int OUTBF>
__global__ __launch_bounds__(256) void gemm_nt(
    const unsigned short* __restrict__ A, const unsigned short* __restrict__ Bt,
    void* __restrict__ Cv, int M, int N, int K,
    const unsigned* __restrict__ red, int redidx)
{
  __shared__ __align__(16) unsigned short As[128 * 64];
  __shared__ __align__(16) unsigned short Bs[128 * 64];
  const int tid = threadIdx.x, l = tid & 63, w = tid >> 6;
  const int m0 = blockIdx.y * 128, n0 = blockIdx.x * 128;
  const int wr = w >> 1, wc = w & 1;
  const int lrow = l >> 3, lsl = l & 7;
  const int srcks = lsl ^ lrow;
  f32x4 acc[4][4];
  #pragma unroll
  for (int a = 0; a < 4; ++a)
    #pragma unroll
    for (int b = 0; b < 4; ++b) { acc[a][b][0] = 0.f; acc[a][b][1] = 0.f; acc[a][b][2] = 0.f; acc[a][b][3] = 0.f; }

  for (int k0 = 0; k0 < K; k0 += 64) {
    #pragma unroll
    for (int j = 0; j < 4; ++j) {
      int c = w * 4 + j;
      int row = c * 8 + lrow;
      gload_lds16(A  + (size_t)(m0 + row) * K + k0 + srcks * 8, (char*)As + c * 1024);
      gload_lds16(Bt + (size_t)(n0 + row) * K + k0 + srcks * 8, (char*)Bs + c * 1024);
    }
    __syncthreads();
    #pragma unroll
    for (int kk = 0; kk < 2; ++kk) {
      short8 af[4], bf[4];
      #pragma unroll
      for (int mi = 0; mi < 4; ++mi) {
        int row = wr * 64 + mi * 16 + (l & 15);
        int slot = (kk * 4 + (l >> 4)) ^ (row & 7);
        af[mi] = *(const short8*)((const char*)As + row * 128 + slot * 16);
      }
      #pragma unroll
      for (int ni = 0; ni < 4; ++ni) {
        int row = wc * 64 + ni * 16 + (l & 15);
        int slot = (kk * 4 + (l >> 4)) ^ (row & 7);
        bf[ni] = *(const short8*)((const char*)Bs + row * 128 + slot * 16);
      }
      #pragma unroll
      for (int mi = 0; mi < 4; ++mi)
        #pragma unroll
        for (int ni = 0; ni < 4; ++ni)
          acc[mi][ni] = mfma16(af[mi], bf[ni], acc[mi][ni]);
    }
    __syncthreads();
  }

  float alpha = 1.0f;
  if (redidx >= 0) alpha = fmaxf(__uint_as_float(red[redidx]), 1e-8f) / 127.0f;
  #pragma unroll
  for (int mi = 0; mi < 4; ++mi) {
    int row = m0 + wr * 64 + mi * 16 + (l >> 4) * 4;
    #pragma unroll
    for (int ni = 0; ni < 4; ++ni) {
      int col = n0 + wc * 64 + ni * 16 + (l & 15);
      #pragma unroll
      for (int i = 0; i < 4; ++i) {
        float v = acc[mi][ni][i] * alpha;
        if constexpr (OUTBF) ((unsigned short*)Cv)[(size_t)(row + i) * N + col] = f2bf(v);
        else                 ((float*)Cv)[(size_t)(row + i) * N + col] = v;
      }
    }
  }
}

// ---------------- K3: rope (recompute, no store) + absmax q,k,v ----------------
__global__ __launch_bounds__(256) void rope_absmax(
    const unsigned short* __restrict__ qkv, const int* __restrict__ pos,
    const float* __restrict__ ct, const float* __restrict__ st,
    unsigned* __restrict__ red)
{
  int t = threadIdx.x;
  int h = t >> 3, jc = (t & 7) * 8;
  float mq = 0.f, mk = 0.f, mv = 0.f;
  for (int bs = blockIdx.x; bs < kM; bs += gridDim.x) {
    int p = pos[bs];
    const unsigned short* row = qkv + (size_t)bs * 12288;
    float cs[8], sn[8];
    #pragma unroll
    for (int e = 0; e < 8; ++e) { cs[e] = ct[p * 64 + jc + e]; sn[e] = st[p * 64 + jc + e]; }
    {
      short8 x1 = *(const short8*)(row + h * 128 + jc);
      short8 x2 = *(const short8*)(row + h * 128 + 64 + jc);
      #pragma unroll
      for (int e = 0; e < 8; ++e) {
        float a = bf2f(x1[e]), b = bf2f(x2[e]);
        mq = fmaxf(mq, fmaxf(fabsf(a * cs[e] - b * sn[e]), fabsf(b * cs[e] + a * sn[e])));
      }
    }
    {
      short8 x1 = *(const short8*)(row + 4096 + h * 128 + jc);
      short8 x2 = *(const short8*)(row + 4096 + h * 128 + 64 + jc);
      #pragma unroll
      for (int e = 0; e < 8; ++e) {
        float a = bf2f(x1[e]), b = bf2f(x2[e]);
        mk = fmaxf(mk, fmaxf(fabsf(a * cs[e] - b * sn[e]), fabsf(b * cs[e] + a * sn[e])));
      }
    }
    {
      short8 v0 = *(const short8*)(row + 8192 + t * 16);
      short8 v1 = *(const short8*)(row + 8192 + t * 16 + 8);
      #pragma unroll
      for (int e = 0; e < 8; ++e) mv = fmaxf(mv, fmaxf(fabsf(bf2f(v0[e])), fabsf(bf2f(v1[e]))));
    }
  }
  mq = wave_max(mq); mk = wave_max(mk); mv = wave_max(mv);
  __shared__ float sm[3][4];
  int w = t >> 6;
  if ((t & 63) == 0) { sm[0][w] = mq; sm[1][w] = mk; sm[2][w] = mv; }
  __syncthreads();
  if (t == 0) {
    atomicMax(red + 0, __float_as_uint(fmaxf(fmaxf(sm[0][0], sm[0][1]), fmaxf(sm[0][2], sm[0][3]))));
    atomicMax(red + 1, __float_as_uint(fmaxf(fmaxf(sm[1][0], sm[1][1]), fmaxf(sm[1][2], sm[1][3]))));
    atomicMax(red + 2, __float_as_uint(fmaxf(fmaxf(sm[2][0], sm[2][1]), fmaxf(sm[2][2], sm[2][3]))));
  }
}

// ---------------- K4: re-apply rope, quantize q,k -> [b][h][s][128] int-bf16 ----------------
__global__ __launch_bounds__(256) void quant_qk_rope(
    const unsigned short* __restrict__ qkv, const int* __restrict__ pos,
    const float* __restrict__ ct, const float* __restrict__ st,
    const unsigned* __restrict__ red,
    unsigned short* __restrict__ qq, unsigned short* __restrict__ kq)
{
  int bs = blockIdx.x, t = threadIdx.x;
  int b = bs >> 10, s = bs & 1023;
  int p = pos[bs];
  float iq = 127.0f / fmaxf(__uint_as_float(red[0]), 1e-8f);
  float ik = 127.0f / fmaxf(__uint_as_float(red[1]), 1e-8f);
  const unsigned short* row = qkv + (size_t)bs * 12288;
  int h = t >> 3, jc = (t & 7) * 8;
  float cs[8], sn[8];
  #pragma unroll
  for (int e = 0; e < 8; ++e) { cs[e] = ct[p * 64 + jc + e]; sn[e] = st[p * 64 + jc + e]; }
  size_t ob = ((size_t)(b * kH + h) * kS + s) * 128;
  {
    short8 x1 = *(const short8*)(row + h * 128 + jc);
    short8 x2 = *(const short8*)(row + h * 128 + 64 + jc);
    short8 o1, o2;
    #pragma unroll
    for (int e = 0; e < 8; ++e) {
      float a = bf2f(x1[e]), b2 = bf2f(x2[e]);
      o1[e] = (short)f2bf(clamp127(rintf((a * cs[e] - b2 * sn[e]) * iq)));
      o2[e] = (short)f2bf(clamp127(rintf((b2 * cs[e] + a * sn[e]) * iq)));
    }
    *(short8*)(qq + ob + jc) = o1;
    *(short8*)(qq + ob + 64 + jc) = o2;
  }
  {
    short8 x1 = *(const short8*)(row + 4096 + h * 128 + jc);
    short8 x2 = *(const short8*)(row + 4096 + h * 128 + 64 + jc);
    short8 o1, o2;
    #pragma unroll
    for (int e = 0; e < 8; ++e) {
      float a = bf2f(x1[e]), b2 = bf2f(x2[e]);
      o1[e] = (short)f2bf(clamp127(rintf((a * cs[e] - b2 * sn[e]) * ik)));
      o2[e] = (short)f2bf(clamp127(rintf((b2 * cs[e] + a * sn[e]) * ik)));
    }
    *(short8*)(kq + ob + jc) = o1;
    *(short8*)(kq + ob + 64 + jc) = o2;
  }
}

// ---------------- K5: quantize + transpose v -> [b*h][hd][s] int-bf16 ----------------
__global__ __launch_bounds__(256) void quantT_v(
    const unsigned short* __restrict__ qkv, const unsigned* __restrict__ red,
    unsigned short* __restrict__ vt)
{
  __shared__ float tile[32][132];
  int bh = blockIdx.x, st0 = blockIdx.y * 32;
  int b = bh >> 5, h = bh & 31;
  float iv = 127.0f / fmaxf(__uint_as_float(red[2]), 1e-8f);
  int t = threadIdx.x;
  #pragma unroll
  for (int e = 0; e < 2; ++e) {
    int idx = (e * 256 + t) * 8;
    int sl = idx >> 7, hd = idx & 127;
    short8 xv = *(const short8*)(qkv + (size_t)(b * 1024 + st0 + sl) * 12288 + 8192 + h * 128 + hd);
    #pragma unroll
    for (int q = 0; q < 8; ++q) tile[sl][hd + q] = clamp127(rintf(bf2f(xv[q]) * iv));
  }
  __syncthreads();
  #pragma unroll
  for (int e = 0; e < 16; ++e) {
    int idx = e * 256 + t;
    int sl = idx & 31, hd = idx >> 5;
    vt[((size_t)bh * 128 + hd) * kS + st0 + sl] = f2bf(tile[sl][hd]);
  }
}

// ---------------- K6: QK^T integer absmax, GEMM-structured ----------------
__global__ __launch_bounds__(256) void qk_absmax_gemm(
    const unsigned short* __restrict__ qq, const unsigned short* __restrict__ kq,
    unsigned* __restrict__ red)
{
  __shared__ __align__(16) unsigned short As[128 * 64];
  __shared__ __align__(16) unsigned short Bs[128 * 64];
  const int tid = threadIdx.x, l = tid & 63, w = tid >> 6;
  const int bh = blockIdx.z;
  const int m0 = blockIdx.y * 128, n0 = blockIdx.x * 128;
  const unsigned short* A  = qq + (size_t)bh * 131072;
  const unsigned short* Bt = kq + (size_t)bh * 131072;
  const int wr = w >> 1, wc = w & 1;
  const int lrow = l >> 3, lsl = l & 7;
  const int srcks = lsl ^ lrow;
  f32x4 acc[4][4];
  #pragma unroll
  for (int a = 0; a < 4; ++a)
    #pragma unroll
    for (int b = 0; b < 4; ++b) { acc[a][b][0] = 0.f; acc[a][b][1] = 0.f; acc[a][b][2] = 0.f; acc[a][b][3] = 0.f; }

  for (int k0 = 0; k0 < 128; k0 += 64) {
    #pragma unroll
    for (int j = 0; j < 4; ++j) {
      int c = w * 4 + j;
      int row = c * 8 + lrow;
      gload_lds16(A  + (size_t)(m0 + row) * 128 + k0 + srcks * 8, (char*)As + c * 1024);
      gload_lds16(Bt + (size_t)(n0 + row) * 128 + k0 + srcks * 8, (char*)Bs + c * 1024);
    }
    __syncthreads();
    #pragma unroll
    for (int kk = 0; kk < 2; ++kk) {
      short8 af[4], bf[4];
      #pragma unroll
      for (int mi = 0; mi < 4; ++mi) {
        int row = wr * 64 + mi * 16 + (l & 15);
        int slot = (kk * 4 + (l >> 4)) ^ (row & 7);
        af[mi] = *(const short8*)((const char*)As + row * 128 + slot * 16);
      }
      #pragma unroll
      for (int ni = 0; ni < 4; ++ni) {
        int row = wc * 64 + ni * 16 + (l & 15);
        int slot = (kk * 4 + (l >> 4)) ^ (row & 7);
        bf[ni] = *(const short8*)((const char*)Bs + row * 128 + slot * 16);
      }
      #pragma unroll
      for (int mi = 0; mi < 4; ++mi)
        #pragma unroll
        for (int ni = 0; ni < 4; ++ni)
          acc[mi][ni] = mfma16(af[mi], bf[ni], acc[mi][ni]);
    }
    __syncthreads();
  }

  float vmax = 0.f;
  #pragma unroll
  for (int mi = 0; mi < 4; ++mi)
    #pragma unroll
    for (int ni = 0; ni < 4; ++ni)
      #pragma unroll
      for (int i = 0; i < 4; ++i) vmax = fmaxf(vmax, fabsf(acc[mi][ni][i]));
  vmax = wave_max(vmax);
  __shared__ float sm[4];
  if (l == 0) sm[w] = vmax;
  __syncthreads();
  if (tid == 0)
    atomicMax(red + 3, __float_as_uint(fmaxf(fmaxf(sm[0], sm[1]), fmaxf(sm[2], sm[3]))));
}

// ---------------- K7: fused QK^T -> quant -> mask -> softmax -> quant -> PV (causal-skip) ----------------
__global__ __launch_bounds__(256) void softmax_pv(
    const unsigned short* __restrict__ qq, const unsigned short* __restrict__ kq,
    const unsigned short* __restrict__ vt,
    unsigned* __restrict__ red, float* __restrict__ ao)
{
  __shared__ unsigned short Lg[16][1024];   // 32 KB, int logits/probs as bf16, XOR-swizzled
  int bh = blockIdx.x, r0 = blockIdx.y * 16;
  int t = threadIdx.x, l = t & 63, w = t >> 6;
  float sq = fmaxf(__uint_as_float(red[0]), 1e-8f) / 127.0f;
  float sk = fmaxf(__uint_as_float(red[1]), 1e-8f) / 127.0f;
  const float c1 = sq * sk * kInvSqrtHD;
  float sl = fmaxf(__uint_as_float(red[3]) * c1, 1e-8f) / 127.0f;
  float isl = 1.0f / sl;
  const unsigned short* qb = qq + (size_t)bh * 131072;
  const unsigned short* kb = kq + (size_t)bh * 131072;
  const unsigned short* vb = vt + (size_t)bh * 131072;
  const int ktop = r0 >> 4;
  const int blimit = r0 + 16;

  short8 aq[4];
  #pragma unroll
  for (int s = 0; s < 4; ++s)
    aq[s] = *(const short8*)(qb + (size_t)(r0 + (l & 15)) * 128 + s * 32 + (l >> 4) * 8);
  for (int kt = w; kt <= ktop; kt += 4) {
    int key0 = kt * 16;
    short8 bq[4];
    #pragma unroll
    for (int s = 0; s < 4; ++s)
      bq[s] = *(const short8*)(kb + (size_t)(key0 + (l & 15)) * 128 + s * 32 + (l >> 4) * 8);
    f32x4 acc; acc[0] = 0.f; acc[1] = 0.f; acc[2] = 0.f; acc[3] = 0.f;
    #pragma unroll
    for (int s = 0; s < 4; ++s) acc = mfma16(aq[s], bq[s], acc);
    int col = key0 + (l & 15);
    #pragma unroll
    for (int i = 0; i < 4; ++i) {
      int rl = (l >> 4) * 4 + i;
      float qv = (col > r0 + rl) ? kMaskVal : clamp127(rintf(acc[i] * c1 * isl));
      Lg[rl][col ^ ((rl & 7) << 3)] = f2bf(qv);
    }
  }
  __syncthreads();

  const int nch = (blimit + 511) >> 9;
  #pragma unroll
  for (int r = 0; r < 4; ++r) {
    int row = w * 4 + r, xm = (row & 7) << 3;
    float vals[2][8];
    float m = kMaskVal;
    for (int j = 0; j < nch; ++j) {
      int base = j * 512 + l * 8;
      short8 v = *(const short8*)&Lg[row][base ^ xm];
      #pragma unroll
      for (int e = 0; e < 8; ++e) {
        float f = (base + e < blimit) ? bf2f(v[e]) : kMaskVal;
        vals[j][e] = f;
        m = fmaxf(m, f);
      }
    }
    m = wave_max(m);
    float sum = 0.f;
    float ex[2][8];
    for (int j = 0; j < nch; ++j)
      #pragma unroll
      for (int e = 0; e < 8; ++e) { ex[j][e] = __expf((vals[j][e] - m) * sl); sum += ex[j][e]; }
    sum = wave_sum(sum);
    float inv127 = 127.0f / sum;
    for (int j = 0; j < nch; ++j) {
      int base = j * 512 + l * 8;
      short8 o;
      #pragma unroll
      for (int e = 0; e < 8; ++e) o[e] = (short)f2bf(rintf(ex[j][e] * inv127));
      *(short8*)&Lg[row][base ^ xm] = o;
    }
  }
  __syncthreads();

  float sv = fmaxf(__uint_as_float(red[2]), 1e-8f) / 127.0f;
  const float c2 = sv * (1.0f / 127.0f);
  const int ksmax = (r0 + 47) >> 5;
  f32x4 pacc[2];
  pacc[0][0]=0.f;pacc[0][1]=0.f;pacc[0][2]=0.f;pacc[0][3]=0.f;
  pacc[1][0]=0.f;pacc[1][1]=0.f;pacc[1][2]=0.f;pacc[1][3]=0.f;
  for (int ks = 0; ks < ksmax; ++ks) {
    int r = l & 15, c0 = ks * 32 + (l >> 4) * 8;
    short8 af = *(const short8*)&Lg[r][c0 ^ ((r & 7) << 3)];
    #pragma unroll
    for (int j = 0; j < 2; ++j) {
      int hd = (w * 2 + j) * 16 + (l & 15);
      short8 bf = *(const short8*)(vb + (size_t)hd * kS + ks * 32 + (l >> 4) * 8);
      pacc[j] = mfma16(af, bf, pacc[j]);
    }
  }
  float vmax = 0.f;
  #pragma unroll
  for (int j = 0; j < 2; ++j) {
    int hd = (w * 2 + j) * 16 + (l & 15);
    int rbase = r0 + (l >> 4) * 4;
    #pragma unroll
    for (int i = 0; i < 4; ++i) {
      float val = pacc[j][i] * c2;
      ao[((size_t)bh * kS + rbase + i) * 128 + hd] = val;
      vmax = fmaxf(vmax, fabsf(val));
    }
  }
  vmax = wave_max(vmax);
  __shared__ float sm2[4];
  if (l == 0) sm2[w] = vmax;
  __syncthreads();
  if (t == 0)
    atomicMax(red + 4, __float_as_uint(fmaxf(fmaxf(sm2[0], sm2[1]), fmaxf(sm2[2], sm2[3]))));
}

// ---------------- K8: quantize attn_out -> int-bf16 [b][s][h*128+hd] ----------------
__global__ __launch_bounds__(256) void quant_ao(
    const float* __restrict__ ao, const unsigned* __restrict__ red,
    unsigned short* __restrict__ aob)
{
  float ia = 127.0f / fmaxf(__uint_as_float(red[4]), 1e-8f);
  const int n = 64 * kS * 128;
  for (int i = blockIdx.x * 256 + threadIdx.x; i < n; i += gridDim.x * 256) {
    int bh = i >> 17, rem = i & 131071;
    int s = rem >> 7, hd = rem & 127;
    int b = bh >> 5, h = bh & 31;
    aob[((size_t)(b * 1024 + s)) * 4096 + h * 128 + hd] = f2bf(clamp127(rintf(ao[i] * ia)));
  }
}

// ---------------- launch ----------------
extern "C" void kernel_launch(void* const* d_in, const int* in_sizes, int n_in,
                              void* d_out, int out_size, void* d_ws, size_t ws_size,
                              hipStream_t stream) {
  const float* hs = (const float*)d_in[0];
  const float* wq = (const float*)d_in[1];
  const float* wk = (const float*)d_in[2];
  const float* wv = (const float*)d_in[3];
  const float* wo = (const float*)d_in[4];
  const int* pos  = (const int*)d_in[5];
  char* ws = (char*)d_ws;

  unsigned short* hs_b   = (unsigned short*)(ws + OFF_A + A_HSB);
  unsigned short* wqkv_b = (unsigned short*)(ws + OFF_A + A_WQKV);
  unsigned short* qq     = (unsigned short*)(ws + OFF_A + A_QQ);
  unsigned short* kq     = (unsigned short*)(ws + OFF_A + A_KQ);
  unsigned short* vt     = (unsigned short*)(ws + OFF_A + A_VT);
  float*          ao     = (float*)(ws + OFF_A + A_AO);
  unsigned short* aob    = (unsigned short*)(ws + OFF_A + A_AOB);
  unsigned short* qkv    = (unsigned short*)(ws + OFF_QKV);
  unsigned short* wo_b   = (unsigned short*)(ws + OFF_QKV);   // after qkv is dead
  float*          rc     = (float*)(ws + OFF_TAB);
  float*          rs     = (float*)(ws + OFF_TAB + 262144);
  unsigned*       red    = (unsigned*)(ws + OFF_RED);

  (void)hipMemsetAsync(red, 0, 256, stream);

  rope_table<<<dim3(256), dim3(256), 0, stream>>>(rc, rs);
  convert_hqkv<<<dim3(2048), dim3(256), 0, stream>>>(hs, wq, wk, wv, hs_b, wqkv_b);
  gemm_nt8<1><<<dim3(48, 8), dim3(512), 0, stream>>>(hs_b, wqkv_b, qkv, kM, 12288, 4096, red, -1);
  rope_absmax<<<dim3(256), dim3(256), 0, stream>>>(qkv, pos, rc, rs, red);
  quant_qk_rope<<<dim3(2048), dim3(256), 0, stream>>>(qkv, pos, rc, rs, red, qq, kq);
  quantT_v<<<dim3(64, 32), dim3(256), 0, stream>>>(qkv, red, vt);
  convert_wo<<<dim3(1024), dim3(256), 0, stream>>>(wo, wo_b);
  qk_absmax_gemm<<<dim3(8, 8, 64), dim3(256), 0, stream>>>(qq, kq, red);
  softmax_pv<<<dim3(64, 64), dim3(256), 0, stream>>>(qq, kq, vt, red, ao);
  quant_ao<<<dim3(2048), dim3(256), 0, stream>>>(ao, red, aob);
  gemm_nt<0><<<dim3(32, 16), dim3(256), 0, stream>>>(aob, wo_b, d_out, kM, 4096, 4096, red, 4);
}